// Round 1
// baseline (495.563 us; speedup 1.0000x reference)
//
#include <hip/hip_runtime.h>

#define NB   1024
#define NN   128
#define NOBS 64
#define NHID 128
#define NACT 9
#define LDW  136
#define NTHR 512

// workspace offsets (in bf16/ushort elements): [hi | lo] per weight, transposed to [dout_pad][din]
#define OFF_ENC 0
#define OFF_V   16384
#define OFF_K   49152
#define OFF_Q   81920
#define OFF_W1  114688
#define OFF_W2  147456
#define OFF_W3  180224
#define OFF_W4  212992

#define SMEM_BYTES 147456  // 4 mats * 17408 shorts * 2B + 128*16 floats

typedef __attribute__((ext_vector_type(8))) short short8;
typedef __attribute__((ext_vector_type(4))) float f32x4;

__device__ __forceinline__ unsigned short bf_rne(float f){
  unsigned u = __float_as_uint(f);
  unsigned r = u + 0x7FFFu + ((u >> 16) & 1u);
  return (unsigned short)(r >> 16);
}
__device__ __forceinline__ float bf_f(unsigned short h){
  return __uint_as_float(((unsigned)h) << 16);
}
__device__ __forceinline__ void splitf(float f, unsigned short& h, unsigned short& l){
  h = bf_rne(f);
  l = bf_rne(f - bf_f(h));
}

// transpose + bf16 hi/lo split of weight w[din][dout] -> hi/lo [dpad][din]
__global__ void prep_w(const float* __restrict__ w, unsigned short* __restrict__ hi,
                       unsigned short* __restrict__ lo, int din, int dout, int dpad){
  int i = blockIdx.x * blockDim.x + threadIdx.x;
  if (i >= dpad * din) return;
  int c = i / din, k = i - c * din;
  float v = (c < dout) ? w[(size_t)k * dout + c] : 0.0f;
  unsigned short h, l; splitf(v, h, l);
  hi[i] = h; lo[i] = l;
}

__device__ __forceinline__ void tf4(unsigned& v0, unsigned& v1, int r0,int r1,int r2,int r3){
  v0 += v1; v1 = (v1<<r0)|(v1>>(32-r0)); v1 ^= v0;
  v0 += v1; v1 = (v1<<r1)|(v1>>(32-r1)); v1 ^= v0;
  v0 += v1; v1 = (v1<<r2)|(v1>>(32-r2)); v1 ^= v0;
  v0 += v1; v1 = (v1<<r3)|(v1>>(32-r3)); v1 ^= v0;
}
// threefry2x32, key = (0, 42) i.e. jax.random.key(42)
__device__ __forceinline__ void threefry(unsigned x0, unsigned x1, unsigned& o0, unsigned& o1){
  const unsigned ks0 = 0u, ks1 = 42u, ks2 = 0x1BD11BDAu ^ 0u ^ 42u;
  unsigned v0 = x0 + ks0, v1 = x1 + ks1;
  tf4(v0,v1,13,15,26,6);  v0 += ks1; v1 += ks2 + 1u;
  tf4(v0,v1,17,29,16,24); v0 += ks2; v1 += ks0 + 2u;
  tf4(v0,v1,13,15,26,6);  v0 += ks0; v1 += ks1 + 3u;
  tf4(v0,v1,17,29,16,24); v0 += ks1; v1 += ks2 + 4u;
  tf4(v0,v1,13,15,26,6);  v0 += ks2; v1 += ks0 + 5u;
  o0 = v0; o1 = v1;
}

#define MFMA(a,b,c) __builtin_amdgcn_mfma_f32_16x16x32_bf16((a),(b),(c),0,0,0)

// out[stripe] = act(A @ W + bias); A from LDS split pair, W from global split pair (pre-transposed [col][k])
template<int K, bool TRANS>
__device__ __forceinline__ void denseW(const short* __restrict__ Ahi, const short* __restrict__ Alo,
                                       const unsigned short* __restrict__ Whi, const unsigned short* __restrict__ Wlo,
                                       const float* __restrict__ bias, short* __restrict__ Ohi, short* __restrict__ Olo,
                                       int wave, int lane, bool dorelu){
  const int l15 = lane & 15, g = lane >> 4;
  f32x4 acc[8];
#pragma unroll
  for (int c = 0; c < 8; ++c) acc[c] = (f32x4){0.f,0.f,0.f,0.f};
  const int abase = (wave*16 + l15)*LDW + 8*g;
#pragma unroll
  for (int kp = 0; kp < K/32; ++kp){
    short8 ah = *(const short8*)(Ahi + abase + kp*32);
    short8 al = *(const short8*)(Alo + abase + kp*32);
#pragma unroll
    for (int c = 0; c < 8; ++c){
      const int wof = (c*16 + l15)*K + kp*32 + 8*g;
      short8 bh = *(const short8*)(Whi + wof);
      short8 bl = *(const short8*)(Wlo + wof);
      acc[c] = MFMA(ah, bh, acc[c]);
      acc[c] = MFMA(ah, bl, acc[c]);
      acc[c] = MFMA(al, bh, acc[c]);
      acc[c] = MFMA(al, bl, acc[c]);
    }
  }
#pragma unroll
  for (int c = 0; c < 8; ++c){
    const int col = c*16 + l15;
    const float bb = bias[col];
#pragma unroll
    for (int i = 0; i < 4; ++i){
      const int row = wave*16 + g*4 + i;
      float v = acc[c][i] + bb;
      if (dorelu) v = fmaxf(v, 0.0f);
      unsigned short h, l; splitf(v, h, l);
      if (TRANS){ Ohi[col*LDW + row] = (short)h; Olo[col*LDW + row] = (short)l; }
      else      { Ohi[row*LDW + col] = (short)h; Olo[row*LDW + col] = (short)l; }
    }
  }
}

__global__ __launch_bounds__(NTHR)
void dgn_main(const float* __restrict__ x, const float* __restrict__ mask,
              const unsigned short* __restrict__ wt,
              const float* __restrict__ encb, const float* __restrict__ bv,
              const float* __restrict__ bk, const float* __restrict__ bq,
              const float* __restrict__ b1, const float* __restrict__ b2,
              const float* __restrict__ b3, const float* __restrict__ b4,
              float* __restrict__ out){
  extern __shared__ char smem[];
  short* SAh = (short*)smem;
  short* SAl = SAh + 17408;
  short* SBh = SAl + 17408;
  short* SBl = SBh + 17408;
  float* LGS = (float*)(smem + 139264);

  const int tid  = threadIdx.x;
  const int lane = tid & 63;
  const int wave = tid >> 6;
  const int l15  = lane & 15;
  const int g    = lane >> 4;
  const int b    = blockIdx.x;

  // ---- P0: stage x[b] (bf16 hi/lo split) into SB
  {
    const float4* xb = (const float4*)(x + (size_t)b * NN * NOBS);
    for (int t = tid; t < NN*NOBS/4; t += NTHR){
      float4 f = xb[t];
      int base = t*4, row = base >> 6, col = base & 63;
      unsigned short h, l;
      splitf(f.x,h,l); SBh[row*LDW+col+0]=(short)h; SBl[row*LDW+col+0]=(short)l;
      splitf(f.y,h,l); SBh[row*LDW+col+1]=(short)h; SBl[row*LDW+col+1]=(short)l;
      splitf(f.z,h,l); SBh[row*LDW+col+2]=(short)h; SBl[row*LDW+col+2]=(short)l;
      splitf(f.w,h,l); SBh[row*LDW+col+3]=(short)h; SBl[row*LDW+col+3]=(short)l;
    }
  }
  __syncthreads();

  // ---- P1: h1 = relu(x @ enc_w + enc_b) -> SA  (per-wave stripe; no cross-wave deps below until P5)
  denseW<NOBS,false>(SBh, SBl, wt+OFF_ENC, wt+OFF_ENC+8192, encb, SAh, SAl, wave, lane, true);
  // ---- P2: q = relu(h1 @ wq + bq) -> SB
  denseW<NHID,false>(SAh, SAl, wt+OFF_Q, wt+OFF_Q+16384, bq, SBh, SBl, wave, lane, true);
  // ---- P3: q fragments -> registers (own stripe only)
  short8 qh[4], ql[4];
  {
    const int abase = (wave*16 + l15)*LDW + 8*g;
#pragma unroll
    for (int kp = 0; kp < 4; ++kp){
      qh[kp] = *(const short8*)(SBh + abase + kp*32);
      ql[kp] = *(const short8*)(SBl + abase + kp*32);
    }
  }
  // ---- P4: k = relu(h1 @ wk + bk) -> SB (overwrites q; q lives in regs)
  denseW<NHID,false>(SAh, SAl, wt+OFF_K, wt+OFF_K+16384, bk, SBh, SBl, wave, lane, true);
  __syncthreads();   // all k rows visible to all waves

  // ---- P5: scores = q @ k^T (regs)
  f32x4 sc[8];
#pragma unroll
  for (int c = 0; c < 8; ++c) sc[c] = (f32x4){0.f,0.f,0.f,0.f};
#pragma unroll
  for (int kp = 0; kp < 4; ++kp){
#pragma unroll
    for (int c = 0; c < 8; ++c){
      const int bof = (c*16 + l15)*LDW + kp*32 + 8*g;
      short8 bh = *(const short8*)(SBh + bof);
      short8 bl = *(const short8*)(SBl + bof);
      sc[c] = MFMA(qh[kp], bh, sc[c]);
      sc[c] = MFMA(qh[kp], bl, sc[c]);
      sc[c] = MFMA(ql[kp], bh, sc[c]);
      sc[c] = MFMA(ql[kp], bl, sc[c]);
    }
  }
  // ---- P6: mask/clip -> h output; row softmax -> att values kept in sc
  float mx[4] = {-3.0e38f,-3.0e38f,-3.0e38f,-3.0e38f};
  {
    const float* mrow = mask + (size_t)b * NN * NN;
    float* hout = out + (size_t)NB*NN + (size_t)b * NN * NN;
#pragma unroll
    for (int c = 0; c < 8; ++c){
      const int col = c*16 + l15;
#pragma unroll
      for (int i = 0; i < 4; ++i){
        const int row = wave*16 + g*4 + i;
        float m = mrow[row*NN + col];
        float s = sc[c][i];
        float hv = fminf(fmaxf(s * m, 0.0f), 9.0e13f) - 9.0e15f * (1.0f - m);
        hout[row*NN + col] = hv;
        sc[c][i] = hv;
        mx[i] = fmaxf(mx[i], hv);
      }
    }
  }
#pragma unroll
  for (int off = 8; off >= 1; off >>= 1){
#pragma unroll
    for (int i = 0; i < 4; ++i) mx[i] = fmaxf(mx[i], __shfl_xor(mx[i], off, 64));
  }
  float sm[4] = {0.f,0.f,0.f,0.f};
#pragma unroll
  for (int c = 0; c < 8; ++c){
#pragma unroll
    for (int i = 0; i < 4; ++i){
      float e = expf(sc[c][i] - mx[i]);
      sc[c][i] = e; sm[i] += e;
    }
  }
#pragma unroll
  for (int off = 8; off >= 1; off >>= 1){
#pragma unroll
    for (int i = 0; i < 4; ++i) sm[i] += __shfl_xor(sm[i], off, 64);
  }
  __syncthreads();   // k reads done -> SB reusable

  // ---- P7: vT = relu(h1 @ wv + bv), stored transposed -> SB
  denseW<NHID,true>(SAh, SAl, wt+OFF_V, wt+OFF_V+16384, bv, SBh, SBl, wave, lane, true);
  // ---- P8: att -> SA (overwrites h1; stripe-local)
#pragma unroll
  for (int c = 0; c < 8; ++c){
    const int col = c*16 + l15;
#pragma unroll
    for (int i = 0; i < 4; ++i){
      const int row = wave*16 + g*4 + i;
      float a = sc[c][i] / sm[i];
      unsigned short h, l; splitf(a, h, l);
      SAh[row*LDW + col] = (short)h;
      SAl[row*LDW + col] = (short)l;
    }
  }
  __syncthreads();   // vT + att complete

  // ---- P9: h2 = att @ v (regs); B-frags read vT rows
  f32x4 h2a[8];
#pragma unroll
  for (int c = 0; c < 8; ++c) h2a[c] = (f32x4){0.f,0.f,0.f,0.f};
  {
    const int abase = (wave*16 + l15)*LDW + 8*g;
#pragma unroll
    for (int kp = 0; kp < 4; ++kp){
      short8 ah = *(const short8*)(SAh + abase + kp*32);
      short8 al = *(const short8*)(SAl + abase + kp*32);
#pragma unroll
      for (int c = 0; c < 8; ++c){
        const int bof = (c*16 + l15)*LDW + kp*32 + 8*g;
        short8 bh = *(const short8*)(SBh + bof);
        short8 bl = *(const short8*)(SBl + bof);
        h2a[c] = MFMA(ah, bh, h2a[c]);
        h2a[c] = MFMA(ah, bl, h2a[c]);
        h2a[c] = MFMA(al, bh, h2a[c]);
        h2a[c] = MFMA(al, bl, h2a[c]);
      }
    }
  }
  // ---- P10: h2 -> SA (no bias, no relu; stripe-local)
#pragma unroll
  for (int c = 0; c < 8; ++c){
    const int col = c*16 + l15;
#pragma unroll
    for (int i = 0; i < 4; ++i){
      const int row = wave*16 + g*4 + i;
      unsigned short h, l; splitf(h2a[c][i], h, l);
      SAh[row*LDW + col] = (short)h;
      SAl[row*LDW + col] = (short)l;
    }
  }
  __syncthreads();   // vT reads done -> SB reusable

  // ---- P11..P13: MLP (stripe-local; no syncs needed)
  denseW<NHID,false>(SAh, SAl, wt+OFF_W1, wt+OFF_W1+16384, b1, SBh, SBl, wave, lane, true);
  denseW<NHID,false>(SBh, SBl, wt+OFF_W2, wt+OFF_W2+16384, b2, SAh, SAl, wave, lane, true);
  denseW<NHID,false>(SAh, SAl, wt+OFF_W3, wt+OFF_W3+16384, b3, SBh, SBl, wave, lane, true);

  // ---- P14: logits = a3 @ w4 + b4 -> LGS [128][16]
  {
    f32x4 acc = (f32x4){0.f,0.f,0.f,0.f};
    const int abase = (wave*16 + l15)*LDW + 8*g;
#pragma unroll
    for (int kp = 0; kp < 4; ++kp){
      short8 ah = *(const short8*)(SBh + abase + kp*32);
      short8 al = *(const short8*)(SBl + abase + kp*32);
      const int wof = l15*NHID + kp*32 + 8*g;
      short8 bh = *(const short8*)(wt + OFF_W4 + wof);
      short8 bl = *(const short8*)(wt + OFF_W4 + 2048 + wof);
      acc = MFMA(ah, bh, acc);
      acc = MFMA(ah, bl, acc);
      acc = MFMA(al, bh, acc);
      acc = MFMA(al, bl, acc);
    }
#pragma unroll
    for (int i = 0; i < 4; ++i){
      const int row = wave*16 + g*4 + i;
      LGS[row*16 + l15] = acc[i] + ((l15 < NACT) ? b4[l15] : 0.0f);
    }
  }
  __syncthreads();

  // ---- P15: log-softmax + threefry-gumbel + argmax -> actions
  if (tid < NN){
    const int r = tid;
    float lg[NACT];
    float mxl = -3.0e38f;
#pragma unroll
    for (int c = 0; c < NACT; ++c){ lg[c] = LGS[r*16 + c]; mxl = fmaxf(mxl, lg[c]); }
    float s = 0.f;
    float p[NACT];
#pragma unroll
    for (int c = 0; c < NACT; ++c){ p[c] = expf(lg[c] - mxl); s += p[c]; }
    const int R = b*NN + r;
    const unsigned HHALF = (unsigned)(NB*NN*NACT/2);  // 589824
    float best = -3.0e38f; int bi = 0;
#pragma unroll
    for (int c = 0; c < NACT; ++c){
      float lp = logf(p[c] / s);
      unsigned e = (unsigned)(R*NACT + c);
      unsigned c0 = (e < HHALF) ? e : (e - HHALF);
      unsigned o0, o1; threefry(c0, c0 + HHALF, o0, o1);
      unsigned bits = (e < HHALF) ? o0 : o1;
      float u = __uint_as_float((bits >> 9) | 0x3f800000u) - 1.0f;
      float uu = fmaxf(1.17549435e-38f, u + 1.17549435e-38f);
      float gmb = -logf(-logf(uu));
      float scv = gmb + lp;
      if (scv > best){ best = scv; bi = c; }
    }
    out[R] = (float)bi;
  }
}

extern "C" void kernel_launch(void* const* d_in, const int* in_sizes, int n_in,
                              void* d_out, int out_size, void* d_ws, size_t ws_size,
                              hipStream_t stream){
  const float* x     = (const float*)d_in[0];
  const float* mask  = (const float*)d_in[1];
  const float* enc_w = (const float*)d_in[2];
  const float* enc_b = (const float*)d_in[3];
  const float* wv    = (const float*)d_in[4];
  const float* bv    = (const float*)d_in[5];
  const float* wk    = (const float*)d_in[6];
  const float* bk    = (const float*)d_in[7];
  const float* wq    = (const float*)d_in[8];
  const float* bq    = (const float*)d_in[9];
  const float* w1    = (const float*)d_in[10];
  const float* b1    = (const float*)d_in[11];
  const float* w2    = (const float*)d_in[12];
  const float* b2    = (const float*)d_in[13];
  const float* w3    = (const float*)d_in[14];
  const float* b3    = (const float*)d_in[15];
  const float* w4    = (const float*)d_in[16];
  const float* b4    = (const float*)d_in[17];
  unsigned short* wt = (unsigned short*)d_ws;
  float* out = (float*)d_out;

  prep_w<<<32, 256, 0, stream>>>(enc_w, wt+OFF_ENC, wt+OFF_ENC+8192, NOBS, NHID, NHID);
  prep_w<<<64, 256, 0, stream>>>(wv, wt+OFF_V, wt+OFF_V+16384, NHID, NHID, NHID);
  prep_w<<<64, 256, 0, stream>>>(wk, wt+OFF_K, wt+OFF_K+16384, NHID, NHID, NHID);
  prep_w<<<64, 256, 0, stream>>>(wq, wt+OFF_Q, wt+OFF_Q+16384, NHID, NHID, NHID);
  prep_w<<<64, 256, 0, stream>>>(w1, wt+OFF_W1, wt+OFF_W1+16384, NHID, NHID, NHID);
  prep_w<<<64, 256, 0, stream>>>(w2, wt+OFF_W2, wt+OFF_W2+16384, NHID, NHID, NHID);
  prep_w<<<64, 256, 0, stream>>>(w3, wt+OFF_W3, wt+OFF_W3+16384, NHID, NHID, NHID);
  prep_w<<<8,  256, 0, stream>>>(w4, wt+OFF_W4, wt+OFF_W4+2048, NHID, NACT, 16);

  (void)hipFuncSetAttribute((const void*)dgn_main,
                            hipFuncAttributeMaxDynamicSharedMemorySize, SMEM_BYTES);
  dgn_main<<<NB, NTHR, SMEM_BYTES, stream>>>(x, mask, wt, enc_b, bv, bk, bq,
                                             b1, b2, b3, b4, out);
}

// Round 2
// 469.097 us; speedup vs baseline: 1.0564x; 1.0564x over previous
//
#include <hip/hip_runtime.h>

#define NB   1024
#define NN   128
#define NOBS 64
#define NHID 128
#define NACT 9
#define NTHR 512

// workspace offsets (ushort elements): [hi | lo] per weight, transposed to [dout_pad][din]
#define OFF_ENC 0
#define OFF_V   16384
#define OFF_K   49152
#define OFF_Q   81920
#define OFF_W1  114688
#define OFF_W2  147456
#define OFF_W3  180224
#define OFF_W4  212992

#define SMEM_BYTES 65536
#define CVS 40   // conversion-chunk row stride (shorts or floats)

typedef __attribute__((ext_vector_type(8))) short short8;
typedef __attribute__((ext_vector_type(4))) float f32x4;

__device__ __forceinline__ unsigned short bf_rne(float f){
  unsigned u = __float_as_uint(f);
  unsigned r = u + 0x7FFFu + ((u >> 16) & 1u);
  return (unsigned short)(r >> 16);
}
__device__ __forceinline__ float bf_f(unsigned short h){
  return __uint_as_float(((unsigned)h) << 16);
}
__device__ __forceinline__ void splitf(float f, unsigned short& h, unsigned short& l){
  h = bf_rne(f);
  l = bf_rne(f - bf_f(h));
}

// transpose + bf16 hi/lo split of weight w[din][dout] -> hi/lo [dpad][din]
__global__ void prep_w(const float* __restrict__ w, unsigned short* __restrict__ hi,
                       unsigned short* __restrict__ lo, int din, int dout, int dpad){
  int i = blockIdx.x * blockDim.x + threadIdx.x;
  if (i >= dpad * din) return;
  int c = i / din, k = i - c * din;
  float v = (c < dout) ? w[(size_t)k * dout + c] : 0.0f;
  unsigned short h, l; splitf(v, h, l);
  hi[i] = h; lo[i] = l;
}

__device__ __forceinline__ void tf4(unsigned& v0, unsigned& v1, int r0,int r1,int r2,int r3){
  v0 += v1; v1 = (v1<<r0)|(v1>>(32-r0)); v1 ^= v0;
  v0 += v1; v1 = (v1<<r1)|(v1>>(32-r1)); v1 ^= v0;
  v0 += v1; v1 = (v1<<r2)|(v1>>(32-r2)); v1 ^= v0;
  v0 += v1; v1 = (v1<<r3)|(v1>>(32-r3)); v1 ^= v0;
}
// threefry2x32, key = (0, 42) i.e. jax.random.key(42)
__device__ __forceinline__ void threefry(unsigned x0, unsigned x1, unsigned& o0, unsigned& o1){
  const unsigned ks0 = 0u, ks1 = 42u, ks2 = 0x1BD11BDAu ^ 0u ^ 42u;
  unsigned v0 = x0 + ks0, v1 = x1 + ks1;
  tf4(v0,v1,13,15,26,6);  v0 += ks1; v1 += ks2 + 1u;
  tf4(v0,v1,17,29,16,24); v0 += ks2; v1 += ks0 + 2u;
  tf4(v0,v1,13,15,26,6);  v0 += ks0; v1 += ks1 + 3u;
  tf4(v0,v1,17,29,16,24); v0 += ks1; v1 += ks2 + 4u;
  tf4(v0,v1,13,15,26,6);  v0 += ks2; v1 += ks0 + 5u;
  o0 = v0; o1 = v1;
}

#define MFMA(a,b,c) __builtin_amdgcn_mfma_f32_16x16x32_bf16((a),(b),(c),0,0,0)
#define MFMA4(ah,al,bh,bl,c) do{ (c)=MFMA((ah),(bh),(c)); (c)=MFMA((ah),(bl),(c)); \
                                 (c)=MFMA((al),(bh),(c)); (c)=MFMA((al),(bl),(c)); }while(0)

// swizzled short-index into a [128][128]-short plane: XOR row&7 into the 16B-granule index
__device__ __forceinline__ int swzi(int row, int col){
  return row*128 + ((((col>>3) ^ (row&7)) & 15)<<3) + (col&7);
}

// write chunk kp (cols 32kp..32kp+31, split hi/lo) of an acc[8] into the wave's CV slot
__device__ __forceinline__ void conv_write(const f32x4* pa, int kp, short* CVh, short* CVl,
                                           int g, int l15){
#pragma unroll
  for (int c2 = 0; c2 < 2; ++c2){
#pragma unroll
    for (int i = 0; i < 4; ++i){
      unsigned short h, l; splitf(pa[2*kp+c2][i], h, l);
      CVh[(4*g+i)*CVS + 16*c2 + l15] = (short)h;
      CVl[(4*g+i)*CVS + 16*c2 + l15] = (short)l;
    }
  }
}

// one dense layer: A = pa (acc layout, finalized) routed via CV chunks; W pre-transposed [128][128]
__device__ __forceinline__ void gemm_CV(const f32x4* pa, const unsigned short* __restrict__ Whi,
                                        const unsigned short* __restrict__ Wlo,
                                        f32x4* acc, short* CVh, short* CVl, int g, int l15){
#pragma unroll
  for (int kp = 0; kp < 4; ++kp){
    conv_write(pa, kp, CVh, CVl, g, l15);
    short8 ah = *(const short8*)(CVh + l15*CVS + 8*g);
    short8 al = *(const short8*)(CVl + l15*CVS + 8*g);
#pragma unroll
    for (int c = 0; c < 8; ++c){
      const int wof = (16*c + l15)*NHID + 32*kp + 8*g;
      short8 bh = *(const short8*)(Whi + wof);
      short8 bl = *(const short8*)(Wlo + wof);
      MFMA4(ah, al, bh, bl, acc[c]);
    }
  }
}

// acc -> A-fragments (row=l15, cols 8g+j+32kp), kept in registers
__device__ __forceinline__ void conv_frags(const f32x4* pa, short8* fh, short8* fl,
                                           short* CVh, short* CVl, int g, int l15){
#pragma unroll
  for (int kp = 0; kp < 4; ++kp){
    conv_write(pa, kp, CVh, CVl, g, l15);
    fh[kp] = *(const short8*)(CVh + l15*CVS + 8*g);
    fl[kp] = *(const short8*)(CVl + l15*CVS + 8*g);
  }
}

__device__ __forceinline__ void finalize(f32x4* acc, const float* __restrict__ bias,
                                         int l15, bool relu){
#pragma unroll
  for (int c = 0; c < 8; ++c){
    float bb = bias[16*c + l15];
#pragma unroll
    for (int i = 0; i < 4; ++i){
      float v = acc[c][i] + bb;
      acc[c][i] = relu ? fmaxf(v, 0.0f) : v;
    }
  }
}

__global__ __launch_bounds__(NTHR, 4)
void dgn_main(const float* __restrict__ x, const float* __restrict__ mask,
              const unsigned short* __restrict__ wt,
              const float* __restrict__ encb, const float* __restrict__ bv,
              const float* __restrict__ bk, const float* __restrict__ bq,
              const float* __restrict__ b1, const float* __restrict__ b2,
              const float* __restrict__ b3, const float* __restrict__ b4,
              float* __restrict__ out){
  extern __shared__ char smem[];
  short* SHh = (short*)smem;          // [128][128] swizzled (k then vT), hi
  short* SHl = SHh + 16384;           // lo
  const int tid  = threadIdx.x;
  const int lane = tid & 63;
  const int w    = tid >> 6;
  const int l15  = lane & 15;
  const int g    = lane >> 4;
  const int b    = blockIdx.x;
  // per-wave 2.5KB conversion slot, OVERLAID on SHh rows; used only while SH content is dead
  short* CVh = (short*)(smem + w*2560);
  short* CVl = CVh + 16*CVS;
  float* CVf = (float*)(smem + w*2560);

  // ---- h1 = relu(x @ enc_w + enc_b) ; x-fragments loaded directly from global
  f32x4 h1a[8];
#pragma unroll
  for (int c = 0; c < 8; ++c) h1a[c] = (f32x4){0.f,0.f,0.f,0.f};
  {
    const float* xrow = x + ((size_t)b*NN + w*16 + l15)*NOBS;
#pragma unroll
    for (int kp = 0; kp < 2; ++kp){
      float4 f0 = *(const float4*)(xrow + 32*kp + 8*g);
      float4 f1 = *(const float4*)(xrow + 32*kp + 8*g + 4);
      float xv[8] = {f0.x,f0.y,f0.z,f0.w,f1.x,f1.y,f1.z,f1.w};
      short8 xh, xl;
#pragma unroll
      for (int j = 0; j < 8; ++j){
        unsigned short h,l; splitf(xv[j],h,l);
        xh[j] = (short)h; xl[j] = (short)l;
      }
#pragma unroll
      for (int c = 0; c < 8; ++c){
        const int wof = (16*c+l15)*NOBS + 32*kp + 8*g;
        short8 bh = *(const short8*)(wt + OFF_ENC + wof);
        short8 bl = *(const short8*)(wt + OFF_ENC + 8192 + wof);
        MFMA4(xh, xl, bh, bl, h1a[c]);
      }
    }
  }
  finalize(h1a, encb, l15, true);

  // ---- q = relu(h1 @ wq + bq) -> fragments in regs
  short8 qfh[4], qfl[4];
  {
    f32x4 qa[8];
#pragma unroll
    for (int c = 0; c < 8; ++c) qa[c] = (f32x4){0.f,0.f,0.f,0.f};
    gemm_CV(h1a, wt+OFF_Q, wt+OFF_Q+16384, qa, CVh, CVl, g, l15);
    finalize(qa, bq, l15, true);
    conv_frags(qa, qfh, qfl, CVh, CVl, g, l15);
  }

  // ---- k = relu(h1 @ wk + bk) -> fragments, then staged to SH (swizzled)
  {
    short8 kfh[4], kfl[4];
    f32x4 ka[8];
#pragma unroll
    for (int c = 0; c < 8; ++c) ka[c] = (f32x4){0.f,0.f,0.f,0.f};
    gemm_CV(h1a, wt+OFF_K, wt+OFF_K+16384, ka, CVh, CVl, g, l15);
    finalize(ka, bk, l15, true);
    conv_frags(ka, kfh, kfl, CVh, CVl, g, l15);
    __syncthreads();   // A': all CV activity done before SH gets live data
#pragma unroll
    for (int kp = 0; kp < 4; ++kp){
      *(short8*)(SHh + swzi(w*16 + l15, 32*kp + 8*g)) = kfh[kp];
      *(short8*)(SHl + swzi(w*16 + l15, 32*kp + 8*g)) = kfl[kp];
    }
  }
  __syncthreads();     // A: k fully staged

  // ---- scores = q @ k^T
  f32x4 sc[8];
#pragma unroll
  for (int c = 0; c < 8; ++c) sc[c] = (f32x4){0.f,0.f,0.f,0.f};
#pragma unroll
  for (int kp = 0; kp < 4; ++kp)
#pragma unroll
    for (int c = 0; c < 8; ++c){
      short8 bh = *(const short8*)(SHh + swzi(16*c+l15, 32*kp+8*g));
      short8 bl = *(const short8*)(SHl + swzi(16*c+l15, 32*kp+8*g));
      MFMA4(qfh[kp], qfl[kp], bh, bl, sc[c]);
    }
  __syncthreads();     // B: k dead -> CV slots usable again

  // ---- mask/clip -> h out (coalesced float4), row softmax, att A-fragments in regs
  float hv[32];
  {
    const float* mrow = mask + (size_t)b*NN*NN + (size_t)(w*16+l15)*NN;
    float* hrow = out + (size_t)NB*NN + (size_t)b*NN*NN + (size_t)(w*16+l15)*NN;
#pragma unroll
    for (int kp = 0; kp < 4; ++kp){
#pragma unroll
      for (int c2 = 0; c2 < 2; ++c2)
#pragma unroll
        for (int i = 0; i < 4; ++i)
          CVf[(4*g+i)*CVS + 16*c2 + l15] = sc[2*kp+c2][i];
      f32x4 s0 = *(const f32x4*)(CVf + l15*CVS + 8*g);
      f32x4 s1 = *(const f32x4*)(CVf + l15*CVS + 8*g + 4);
      float4 m0 = *(const float4*)(mrow + 32*kp + 8*g);
      float4 m1 = *(const float4*)(mrow + 32*kp + 8*g + 4);
      float sv[8] = {s0[0],s0[1],s0[2],s0[3],s1[0],s1[1],s1[2],s1[3]};
      float mv[8] = {m0.x,m0.y,m0.z,m0.w,m1.x,m1.y,m1.z,m1.w};
      float ho[8];
#pragma unroll
      for (int j = 0; j < 8; ++j){
        float hvv = fminf(fmaxf(sv[j]*mv[j], 0.0f), 9.0e13f) - 9.0e15f*(1.0f - mv[j]);
        hv[8*kp + j] = hvv; ho[j] = hvv;
      }
      *(float4*)(hrow + 32*kp + 8*g)     = (float4){ho[0],ho[1],ho[2],ho[3]};
      *(float4*)(hrow + 32*kp + 8*g + 4) = (float4){ho[4],ho[5],ho[6],ho[7]};
    }
  }
  short8 afh[4], afl[4];
  {
    float mx = -3.0e38f;
#pragma unroll
    for (int t = 0; t < 32; ++t) mx = fmaxf(mx, hv[t]);
    mx = fmaxf(mx, __shfl_xor(mx, 16, 64));
    mx = fmaxf(mx, __shfl_xor(mx, 32, 64));
    float sm = 0.f;
#pragma unroll
    for (int t = 0; t < 32; ++t){ hv[t] = expf(hv[t] - mx); sm += hv[t]; }
    sm += __shfl_xor(sm, 16, 64);
    sm += __shfl_xor(sm, 32, 64);
    float inv = 1.0f / sm;
#pragma unroll
    for (int kp = 0; kp < 4; ++kp)
#pragma unroll
      for (int j = 0; j < 8; ++j){
        unsigned short h,l; splitf(hv[8*kp+j]*inv, h, l);
        afh[kp][j] = (short)h; afl[kp][j] = (short)l;
      }
  }

  // ---- v = relu(h1 @ wv + bv) -> vT staged to SH (swizzled, transposed)
  {
    f32x4 va[8];
#pragma unroll
    for (int c = 0; c < 8; ++c) va[c] = (f32x4){0.f,0.f,0.f,0.f};
    gemm_CV(h1a, wt+OFF_V, wt+OFF_V+16384, va, CVh, CVl, g, l15);
    finalize(va, bv, l15, true);
    __syncthreads();   // C1: all CV activity (softmax conv + v conv) done
#pragma unroll
    for (int c = 0; c < 8; ++c)
#pragma unroll
      for (int i = 0; i < 4; ++i){
        unsigned short h,l; splitf(va[c][i], h, l);
        const int idx = swzi(16*c + l15, w*16 + 4*g + i);
        SHh[idx] = (short)h; SHl[idx] = (short)l;
      }
  }
  __syncthreads();     // C: vT fully staged

  // ---- h2 = att @ v
  f32x4 h2a[8];
#pragma unroll
  for (int c = 0; c < 8; ++c) h2a[c] = (f32x4){0.f,0.f,0.f,0.f};
#pragma unroll
  for (int kp = 0; kp < 4; ++kp)
#pragma unroll
    for (int c = 0; c < 8; ++c){
      short8 bh = *(const short8*)(SHh + swzi(16*c+l15, 32*kp+8*g));
      short8 bl = *(const short8*)(SHl + swzi(16*c+l15, 32*kp+8*g));
      MFMA4(afh[kp], afl[kp], bh, bl, h2a[c]);
    }
  __syncthreads();     // D: vT dead -> CV slots usable for MLP

  // ---- MLP (stripe-local, barrier-free)
  f32x4 a1[8], a2[8], a3[8];
#pragma unroll
  for (int c = 0; c < 8; ++c) a1[c] = (f32x4){0.f,0.f,0.f,0.f};
  gemm_CV(h2a, wt+OFF_W1, wt+OFF_W1+16384, a1, CVh, CVl, g, l15);
  finalize(a1, b1, l15, true);
#pragma unroll
  for (int c = 0; c < 8; ++c) a2[c] = (f32x4){0.f,0.f,0.f,0.f};
  gemm_CV(a1, wt+OFF_W2, wt+OFF_W2+16384, a2, CVh, CVl, g, l15);
  finalize(a2, b2, l15, true);
#pragma unroll
  for (int c = 0; c < 8; ++c) a3[c] = (f32x4){0.f,0.f,0.f,0.f};
  gemm_CV(a2, wt+OFF_W3, wt+OFF_W3+16384, a3, CVh, CVl, g, l15);
  finalize(a3, b3, l15, true);

  // ---- logits = a3 @ w4 + b4 (16-col padded weight)
  f32x4 la = (f32x4){0.f,0.f,0.f,0.f};
#pragma unroll
  for (int kp = 0; kp < 4; ++kp){
    conv_write(a3, kp, CVh, CVl, g, l15);
    short8 ah = *(const short8*)(CVh + l15*CVS + 8*g);
    short8 al = *(const short8*)(CVl + l15*CVS + 8*g);
    const int wof = l15*NHID + 32*kp + 8*g;
    short8 bh = *(const short8*)(wt + OFF_W4 + wof);
    short8 bl = *(const short8*)(wt + OFF_W4 + 2048 + wof);
    MFMA4(ah, al, bh, bl, la);
  }
#pragma unroll
  for (int i = 0; i < 4; ++i)
    CVf[(4*g+i)*CVS + l15] = la[i] + ((l15 < NACT) ? b4[l15] : 0.0f);

  // ---- log-softmax + threefry-gumbel + argmax (lanes g==0 take 1 row each)
  if (g == 0){
    float lg[NACT]; float mxl = -3.0e38f;
#pragma unroll
    for (int c = 0; c < NACT; ++c){ lg[c] = CVf[l15*CVS + c]; mxl = fmaxf(mxl, lg[c]); }
    float s = 0.f; float p[NACT];
#pragma unroll
    for (int c = 0; c < NACT; ++c){ p[c] = expf(lg[c] - mxl); s += p[c]; }
    const int R = b*NN + w*16 + l15;
    const unsigned HHALF = (unsigned)(NB*NN*NACT/2);  // 589824
    float best = -3.0e38f; int bi = 0;
#pragma unroll
    for (int c = 0; c < NACT; ++c){
      float lp = logf(p[c] / s);
      unsigned e = (unsigned)(R*NACT + c);
      unsigned c0 = (e < HHALF) ? e : (e - HHALF);
      unsigned o0, o1; threefry(c0, c0 + HHALF, o0, o1);
      unsigned bits = (e < HHALF) ? o0 : o1;
      float u = __uint_as_float((bits >> 9) | 0x3f800000u) - 1.0f;
      float uu = fmaxf(1.17549435e-38f, u + 1.17549435e-38f);
      float gmb = -logf(-logf(uu));
      float scv = gmb + lp;
      if (scv > best){ best = scv; bi = c; }
    }
    out[R] = (float)bi;
  }
}

extern "C" void kernel_launch(void* const* d_in, const int* in_sizes, int n_in,
                              void* d_out, int out_size, void* d_ws, size_t ws_size,
                              hipStream_t stream){
  const float* x     = (const float*)d_in[0];
  const float* mask  = (const float*)d_in[1];
  const float* enc_w = (const float*)d_in[2];
  const float* enc_b = (const float*)d_in[3];
  const float* wv    = (const float*)d_in[4];
  const float* bv    = (const float*)d_in[5];
  const float* wk    = (const float*)d_in[6];
  const float* bk    = (const float*)d_in[7];
  const float* wq    = (const float*)d_in[8];
  const float* bq    = (const float*)d_in[9];
  const float* w1    = (const float*)d_in[10];
  const float* b1    = (const float*)d_in[11];
  const float* w2    = (const float*)d_in[12];
  const float* b2    = (const float*)d_in[13];
  const float* w3    = (const float*)d_in[14];
  const float* b3    = (const float*)d_in[15];
  const float* w4    = (const float*)d_in[16];
  const float* b4    = (const float*)d_in[17];
  unsigned short* wt = (unsigned short*)d_ws;
  float* out = (float*)d_out;

  prep_w<<<32, 256, 0, stream>>>(enc_w, wt+OFF_ENC, wt+OFF_ENC+8192, NOBS, NHID, NHID);
  prep_w<<<64, 256, 0, stream>>>(wv, wt+OFF_V, wt+OFF_V+16384, NHID, NHID, NHID);
  prep_w<<<64, 256, 0, stream>>>(wk, wt+OFF_K, wt+OFF_K+16384, NHID, NHID, NHID);
  prep_w<<<64, 256, 0, stream>>>(wq, wt+OFF_Q, wt+OFF_Q+16384, NHID, NHID, NHID);
  prep_w<<<64, 256, 0, stream>>>(w1, wt+OFF_W1, wt+OFF_W1+16384, NHID, NHID, NHID);
  prep_w<<<64, 256, 0, stream>>>(w2, wt+OFF_W2, wt+OFF_W2+16384, NHID, NHID, NHID);
  prep_w<<<64, 256, 0, stream>>>(w3, wt+OFF_W3, wt+OFF_W3+16384, NHID, NHID, NHID);
  prep_w<<<8,  256, 0, stream>>>(w4, wt+OFF_W4, wt+OFF_W4+2048, NHID, NACT, 16);

  (void)hipFuncSetAttribute((const void*)dgn_main,
                            hipFuncAttributeMaxDynamicSharedMemorySize, SMEM_BYTES);
  dgn_main<<<NB, NTHR, SMEM_BYTES, stream>>>(x, mask, wt, enc_b, bv, bk, bq,
                                             b1, b2, b3, b4, out);
}

// Round 3
// 446.453 us; speedup vs baseline: 1.1100x; 1.0507x over previous
//
#include <hip/hip_runtime.h>

#define NB   1024
#define NN   128
#define NOBS 64
#define NHID 128
#define NACT 9
#define NTHR 512
#define CVS  44   // CV scratch row stride in dwords (16B-aligned rows, low bank conflict)

// workspace offsets (ushort elements): [hi | lo] per weight, transposed to [dout_pad][din]
#define OFF_ENC 0
#define OFF_V   16384
#define OFF_K   49152
#define OFF_Q   81920
#define OFF_W1  114688
#define OFF_W2  147456
#define OFF_W3  180224
#define OFF_W4  212992

#define SMEM_BYTES 65536

typedef __attribute__((ext_vector_type(8))) short short8;
typedef __attribute__((ext_vector_type(4))) float f32x4;
typedef __attribute__((ext_vector_type(2))) unsigned uvec2;

union S8U { short8 s; unsigned u[4]; };

// ---------- RNE split (weights, one-time prep) ----------
__device__ __forceinline__ unsigned short bf_rne(float f){
  unsigned u = __float_as_uint(f);
  unsigned r = u + 0x7FFFu + ((u >> 16) & 1u);
  return (unsigned short)(r >> 16);
}
__device__ __forceinline__ float bf_f(unsigned short h){
  return __uint_as_float(((unsigned)h) << 16);
}
__global__ void prep_w(const float* __restrict__ w, unsigned short* __restrict__ hi,
                       unsigned short* __restrict__ lo, int din, int dout, int dpad){
  int i = blockIdx.x * blockDim.x + threadIdx.x;
  if (i >= dpad * din) return;
  int c = i / din, k = i - c * din;
  float v = (c < dout) ? w[(size_t)k * dout + c] : 0.0f;
  unsigned short h = bf_rne(v);
  unsigned short l = bf_rne(v - bf_f(h));
  hi[i] = h; lo[i] = l;
}

// ---------- fast activation split: hi = RTA-bf16 (top16), lo = rounded remainder ----------
__device__ __forceinline__ void rta_split(float f, unsigned& h, unsigned& l){
  unsigned u = __float_as_uint(f);
  h = (u + 0x8000u) & 0xFFFF0000u;          // |f - hi| <= 2^-9 |f|
  float d = f - __uint_as_float(h);         // exact (Sterbenz)
  l = __float_as_uint(d) + 0x8000u;         // top16 = round-half-up bf16 of d
}
// 8 floats -> packed hi/lo bf16 fragments via v_perm
__device__ __forceinline__ void pack_split8(const float* fv, short8& ah, short8& al){
  unsigned hu[8], lu[8];
#pragma unroll
  for (int j = 0; j < 8; ++j) rta_split(fv[j], hu[j], lu[j]);
  S8U H, L;
#pragma unroll
  for (int j = 0; j < 4; ++j){
    H.u[j] = __builtin_amdgcn_perm(hu[2*j+1], hu[2*j], 0x07060302u);
    L.u[j] = __builtin_amdgcn_perm(lu[2*j+1], lu[2*j], 0x07060302u);
  }
  ah = H.s; al = L.s;
}

// ---------- threefry2x32, key = (0, 42) ----------
__device__ __forceinline__ void tf4(unsigned& v0, unsigned& v1, int r0,int r1,int r2,int r3){
  v0 += v1; v1 = (v1<<r0)|(v1>>(32-r0)); v1 ^= v0;
  v0 += v1; v1 = (v1<<r1)|(v1>>(32-r1)); v1 ^= v0;
  v0 += v1; v1 = (v1<<r2)|(v1>>(32-r2)); v1 ^= v0;
  v0 += v1; v1 = (v1<<r3)|(v1>>(32-r3)); v1 ^= v0;
}
__device__ __forceinline__ void threefry(unsigned x0, unsigned x1, unsigned& o0, unsigned& o1){
  const unsigned ks0 = 0u, ks1 = 42u, ks2 = 0x1BD11BDAu ^ 0u ^ 42u;
  unsigned v0 = x0 + ks0, v1 = x1 + ks1;
  tf4(v0,v1,13,15,26,6);  v0 += ks1; v1 += ks2 + 1u;
  tf4(v0,v1,17,29,16,24); v0 += ks2; v1 += ks0 + 2u;
  tf4(v0,v1,13,15,26,6);  v0 += ks0; v1 += ks1 + 3u;
  tf4(v0,v1,17,29,16,24); v0 += ks1; v1 += ks2 + 4u;
  tf4(v0,v1,13,15,26,6);  v0 += ks2; v1 += ks0 + 5u;
  o0 = v0; o1 = v1;
}

#define MFMA(a,b,c) __builtin_amdgcn_mfma_f32_16x16x32_bf16((a),(b),(c),0,0,0)
#define MFMA4(ah,al,bh,bl,c) do{ (c)=MFMA((ah),(bh),(c)); (c)=MFMA((ah),(bl),(c)); \
                                 (c)=MFMA((al),(bh),(c)); (c)=MFMA((al),(bl),(c)); }while(0)

// swizzled short-index into a [128][128]-short plane: XOR row&7 into the 16B-granule index
__device__ __forceinline__ int swzi(int row, int col){
  return row*128 + ((((col>>3) ^ (row&7)) & 15)<<3) + (col&7);
}

__device__ __forceinline__ void zero8(f32x4* a){
#pragma unroll
  for (int c = 0; c < 8; ++c) a[c] = (f32x4){0.f,0.f,0.f,0.f};
}

// store acc chunk kp (cols 32kp..32kp+31) as raw f32 into the wave's CV slot
__device__ __forceinline__ void cv_put(const f32x4* pa, int kp, float* CVf, int g, int l15){
#pragma unroll
  for (int i = 0; i < 4; ++i){
    float* p = CVf + (4*g + i)*CVS + l15;
    p[0]  = pa[2*kp+0][i];
    p[16] = pa[2*kp+1][i];
  }
}
// read own A-frag row (8 f32), split+pack
__device__ __forceinline__ void cv_get(const float* CVf, int g, int l15, short8& ah, short8& al){
  const float* p = CVf + l15*CVS + 8*g;
  f32x4 f0 = *(const f32x4*)p;
  f32x4 f1 = *(const f32x4*)(p + 4);
  float fv[8] = {f0[0],f0[1],f0[2],f0[3],f1[0],f1[1],f1[2],f1[3]};
  pack_split8(fv, ah, al);
}
// full acc -> 4 fragment pairs (chunk-by-chunk through the 2.75KB CV slot)
__device__ __forceinline__ void conv_all(const f32x4* pa, float* CVf, int g, int l15,
                                         short8* fh, short8* fl){
#pragma unroll
  for (int kp = 0; kp < 4; ++kp){
    cv_put(pa, kp, CVf, g, l15);
    cv_get(CVf, g, l15, fh[kp], fl[kp]);
  }
}

__device__ __forceinline__ void finalize(f32x4* acc, const float* __restrict__ bias,
                                         int l15, bool relu){
#pragma unroll
  for (int c = 0; c < 8; ++c){
    float bb = bias[16*c + l15];
#pragma unroll
    for (int i = 0; i < 4; ++i){
      float v = acc[c][i] + bb;
      acc[c][i] = relu ? fmaxf(v, 0.0f) : v;
    }
  }
}

// dense layer from register fragments; W pre-transposed [dout][K] hi/lo
template<int K>
__device__ __forceinline__ void gemm_frag(const short8* fh, const short8* fl,
                                          const unsigned short* __restrict__ Whi,
                                          const unsigned short* __restrict__ Wlo,
                                          f32x4* acc, int g, int l15){
#pragma unroll
  for (int kp = 0; kp < K/32; ++kp){
#pragma unroll
    for (int c = 0; c < 8; ++c){
      const int wof = (16*c + l15)*K + 32*kp + 8*g;
      short8 bh = *(const short8*)(Whi + wof);
      short8 bl = *(const short8*)(Wlo + wof);
      MFMA4(fh[kp], fl[kp], bh, bl, acc[c]);
    }
  }
}

__attribute__((amdgpu_waves_per_eu(4, 4)))
__global__ void __launch_bounds__(NTHR)
dgn_main(const float* __restrict__ x, const float* __restrict__ mask,
         const unsigned short* __restrict__ wt,
         const float* __restrict__ encb, const float* __restrict__ bv,
         const float* __restrict__ bk, const float* __restrict__ bq,
         const float* __restrict__ b1, const float* __restrict__ b2,
         const float* __restrict__ b3, const float* __restrict__ b4,
         float* __restrict__ out){
  extern __shared__ char smem[];
  short* SHh = (short*)smem;          // [128][128] swizzled shared plane (k then vT), hi
  short* SHl = SHh + 16384;           // lo
  const int tid  = threadIdx.x;
  const int lane = tid & 63;
  const int w    = tid >> 6;
  const int l15  = lane & 15;
  const int g    = lane >> 4;
  const int b    = blockIdx.x;
  // per-wave 2.75KB f32 conversion slot, overlaid on SH; used only while SH content is dead
  float* CVf = (float*)(smem + w*(16*CVS*4));

  f32x4 acc[8];

  // ---- P1: h1 = relu(x @ enc_w + enc_b); x frags straight from global
  zero8(acc);
  {
    short8 xh[2], xl[2];
    const float* xrow = x + ((size_t)b*NN + w*16 + l15)*NOBS;
#pragma unroll
    for (int kp = 0; kp < 2; ++kp){
      float4 f0 = *(const float4*)(xrow + 32*kp + 8*g);
      float4 f1 = *(const float4*)(xrow + 32*kp + 8*g + 4);
      float fv[8] = {f0.x,f0.y,f0.z,f0.w,f1.x,f1.y,f1.z,f1.w};
      pack_split8(fv, xh[kp], xl[kp]);
    }
    gemm_frag<NOBS>(xh, xl, wt+OFF_ENC, wt+OFF_ENC+8192, acc, g, l15);
  }
  finalize(acc, encb, l15, true);
  short8 h1h[4], h1l[4];
  conv_all(acc, CVf, g, l15, h1h, h1l);      // h1 converted ONCE, reused for q/k/v

  // ---- P2: q = relu(h1 @ wq + bq) -> frags in regs
  zero8(acc);
  gemm_frag<NHID>(h1h, h1l, wt+OFF_Q, wt+OFF_Q+16384, acc, g, l15);
  finalize(acc, bq, l15, true);
  short8 qfh[4], qfl[4];
  conv_all(acc, CVf, g, l15, qfh, qfl);

  // ---- P3: k = relu(h1 @ wk + bk) -> frags, staged to SH after barrier
  zero8(acc);
  gemm_frag<NHID>(h1h, h1l, wt+OFF_K, wt+OFF_K+16384, acc, g, l15);
  finalize(acc, bk, l15, true);
  {
    short8 kfh[4], kfl[4];
    conv_all(acc, CVf, g, l15, kfh, kfl);
    __syncthreads();   // [A] all CV activity quiet before SH gets live data
#pragma unroll
    for (int kp = 0; kp < 4; ++kp){
      *(short8*)(SHh + swzi(w*16 + l15, 32*kp + 8*g)) = kfh[kp];
      *(short8*)(SHl + swzi(w*16 + l15, 32*kp + 8*g)) = kfl[kp];
    }
  }
  __syncthreads();     // [B] k fully staged

  // ---- P4: scores = q @ k^T
  f32x4 sc[8];
  zero8(sc);
#pragma unroll
  for (int kp = 0; kp < 4; ++kp)
#pragma unroll
    for (int c = 0; c < 8; ++c){
      short8 bh = *(const short8*)(SHh + swzi(16*c+l15, 32*kp+8*g));
      short8 bl = *(const short8*)(SHl + swzi(16*c+l15, 32*kp+8*g));
      MFMA4(qfh[kp], qfl[kp], bh, bl, sc[c]);
    }
  __syncthreads();     // [C] k dead -> CV usable, SH writable

  // ---- P5: v = relu(h1 @ wv + bv) (kept in acc; h1 frags die here)
  zero8(acc);
  gemm_frag<NHID>(h1h, h1l, wt+OFF_V, wt+OFF_V+16384, acc, g, l15);
  finalize(acc, bv, l15, true);

  // ---- P6: mask/clip -> h out (coalesced), row softmax, att frags in regs
  float hv[32];
  {
    const float* mrow = mask + (size_t)b*NN*NN + (size_t)(w*16+l15)*NN;
    float* hrow = out + (size_t)NB*NN + (size_t)b*NN*NN + (size_t)(w*16+l15)*NN;
#pragma unroll
    for (int kp = 0; kp < 4; ++kp){
      cv_put(sc, kp, CVf, g, l15);
      const float* p = CVf + l15*CVS + 8*g;
      f32x4 s0 = *(const f32x4*)p;
      f32x4 s1 = *(const f32x4*)(p + 4);
      float4 m0 = *(const float4*)(mrow + 32*kp + 8*g);
      float4 m1 = *(const float4*)(mrow + 32*kp + 8*g + 4);
      float sv[8] = {s0[0],s0[1],s0[2],s0[3],s1[0],s1[1],s1[2],s1[3]};
      float mv[8] = {m0.x,m0.y,m0.z,m0.w,m1.x,m1.y,m1.z,m1.w};
      float ho[8];
#pragma unroll
      for (int j = 0; j < 8; ++j){
        float t = fminf(fmaxf(sv[j]*mv[j], 0.0f), 9.0e13f) - 9.0e15f*(1.0f - mv[j]);
        hv[8*kp+j] = t; ho[j] = t;
      }
      *(float4*)(hrow + 32*kp + 8*g)     = (float4){ho[0],ho[1],ho[2],ho[3]};
      *(float4*)(hrow + 32*kp + 8*g + 4) = (float4){ho[4],ho[5],ho[6],ho[7]};
    }
  }
  short8 afh[4], afl[4];
  {
    float mx = -3.0e38f;
#pragma unroll
    for (int t = 0; t < 32; ++t) mx = fmaxf(mx, hv[t]);
    mx = fmaxf(mx, __shfl_xor(mx, 16, 64));
    mx = fmaxf(mx, __shfl_xor(mx, 32, 64));
    float sm = 0.f;
#pragma unroll
    for (int t = 0; t < 32; ++t){ hv[t] = expf(hv[t] - mx); sm += hv[t]; }
    sm += __shfl_xor(sm, 16, 64);
    sm += __shfl_xor(sm, 32, 64);
    float inv = 1.0f / sm;
#pragma unroll
    for (int kp = 0; kp < 4; ++kp){
      float fv[8];
#pragma unroll
      for (int j = 0; j < 8; ++j) fv[j] = hv[8*kp+j]*inv;
      pack_split8(fv, afh[kp], afl[kp]);
    }
  }
  __syncthreads();     // [C1] softmax CV use quiet

  // ---- P7: stage vT (transposed, packed b64 stores)
#pragma unroll
  for (int c = 0; c < 8; ++c){
    unsigned hu[4], lu[4];
#pragma unroll
    for (int i = 0; i < 4; ++i) rta_split(acc[c][i], hu[i], lu[i]);
    uvec2 hp, lp;
    hp[0] = __builtin_amdgcn_perm(hu[1], hu[0], 0x07060302u);
    hp[1] = __builtin_amdgcn_perm(hu[3], hu[2], 0x07060302u);
    lp[0] = __builtin_amdgcn_perm(lu[1], lu[0], 0x07060302u);
    lp[1] = __builtin_amdgcn_perm(lu[3], lu[2], 0x07060302u);
    const int idx = swzi(16*c + l15, w*16 + 4*g);
    *(uvec2*)(SHh + idx) = hp;
    *(uvec2*)(SHl + idx) = lp;
  }
  __syncthreads();     // [D] vT staged

  // ---- P8: h2 = att @ v
  zero8(acc);
#pragma unroll
  for (int kp = 0; kp < 4; ++kp)
#pragma unroll
    for (int c = 0; c < 8; ++c){
      short8 bh = *(const short8*)(SHh + swzi(16*c+l15, 32*kp+8*g));
      short8 bl = *(const short8*)(SHl + swzi(16*c+l15, 32*kp+8*g));
      MFMA4(afh[kp], afl[kp], bh, bl, acc[c]);
    }
  __syncthreads();     // [E] vT dead -> CV free for MLP

  // ---- P9: MLP chain (wave-local, barrier-free)
  short8 fh[4], fl[4];
  conv_all(acc, CVf, g, l15, fh, fl);        // h2 frags (no bias/relu)
  zero8(acc);
  gemm_frag<NHID>(fh, fl, wt+OFF_W1, wt+OFF_W1+16384, acc, g, l15);
  finalize(acc, b1, l15, true);
  conv_all(acc, CVf, g, l15, fh, fl);
  zero8(acc);
  gemm_frag<NHID>(fh, fl, wt+OFF_W2, wt+OFF_W2+16384, acc, g, l15);
  finalize(acc, b2, l15, true);
  conv_all(acc, CVf, g, l15, fh, fl);
  zero8(acc);
  gemm_frag<NHID>(fh, fl, wt+OFF_W3, wt+OFF_W3+16384, acc, g, l15);
  finalize(acc, b3, l15, true);
  conv_all(acc, CVf, g, l15, fh, fl);

  // ---- P10: logits = a3 @ w4 + b4 (16-col padded weight)
  f32x4 la = (f32x4){0.f,0.f,0.f,0.f};
#pragma unroll
  for (int kp = 0; kp < 4; ++kp){
    const int wof = l15*NHID + 32*kp + 8*g;
    short8 bh = *(const short8*)(wt + OFF_W4 + wof);
    short8 bl = *(const short8*)(wt + OFF_W4 + 2048 + wof);
    MFMA4(fh[kp], fl[kp], bh, bl, la);
  }
#pragma unroll
  for (int i = 0; i < 4; ++i)
    CVf[(4*g+i)*CVS + l15] = la[i] + ((l15 < NACT) ? b4[l15] : 0.0f);

  // ---- P11: log-softmax + threefry-gumbel + argmax (lanes g==0, one row each)
  if (g == 0){
    float lg[NACT]; float mxl = -3.0e38f;
#pragma unroll
    for (int c = 0; c < NACT; ++c){ lg[c] = CVf[l15*CVS + c]; mxl = fmaxf(mxl, lg[c]); }
    float s = 0.f; float p[NACT];
#pragma unroll
    for (int c = 0; c < NACT; ++c){ p[c] = expf(lg[c] - mxl); s += p[c]; }
    const int R = b*NN + w*16 + l15;
    const unsigned HHALF = (unsigned)(NB*NN*NACT/2);  // 589824
    float best = -3.0e38f; int bi = 0;
#pragma unroll
    for (int c = 0; c < NACT; ++c){
      float lp = logf(p[c] / s);
      unsigned e = (unsigned)(R*NACT + c);
      unsigned c0 = (e < HHALF) ? e : (e - HHALF);
      unsigned o0, o1; threefry(c0, c0 + HHALF, o0, o1);
      unsigned bits = (e < HHALF) ? o0 : o1;
      float u = __uint_as_float((bits >> 9) | 0x3f800000u) - 1.0f;
      float uu = fmaxf(1.17549435e-38f, u + 1.17549435e-38f);
      float gmb = -logf(-logf(uu));
      float scv = gmb + lp;
      if (scv > best){ best = scv; bi = c; }
    }
    out[R] = (float)bi;
  }
}

extern "C" void kernel_launch(void* const* d_in, const int* in_sizes, int n_in,
                              void* d_out, int out_size, void* d_ws, size_t ws_size,
                              hipStream_t stream){
  const float* x     = (const float*)d_in[0];
  const float* mask  = (const float*)d_in[1];
  const float* enc_w = (const float*)d_in[2];
  const float* enc_b = (const float*)d_in[3];
  const float* wv    = (const float*)d_in[4];
  const float* bv    = (const float*)d_in[5];
  const float* wk    = (const float*)d_in[6];
  const float* bk    = (const float*)d_in[7];
  const float* wq    = (const float*)d_in[8];
  const float* bq    = (const float*)d_in[9];
  const float* w1    = (const float*)d_in[10];
  const float* b1    = (const float*)d_in[11];
  const float* w2    = (const float*)d_in[12];
  const float* b2    = (const float*)d_in[13];
  const float* w3    = (const float*)d_in[14];
  const float* b3    = (const float*)d_in[15];
  const float* w4    = (const float*)d_in[16];
  const float* b4    = (const float*)d_in[17];
  unsigned short* wt = (unsigned short*)d_ws;
  float* out = (float*)d_out;

  prep_w<<<32, 256, 0, stream>>>(enc_w, wt+OFF_ENC, wt+OFF_ENC+8192, NOBS, NHID, NHID);
  prep_w<<<64, 256, 0, stream>>>(wv, wt+OFF_V, wt+OFF_V+16384, NHID, NHID, NHID);
  prep_w<<<64, 256, 0, stream>>>(wk, wt+OFF_K, wt+OFF_K+16384, NHID, NHID, NHID);
  prep_w<<<64, 256, 0, stream>>>(wq, wt+OFF_Q, wt+OFF_Q+16384, NHID, NHID, NHID);
  prep_w<<<64, 256, 0, stream>>>(w1, wt+OFF_W1, wt+OFF_W1+16384, NHID, NHID, NHID);
  prep_w<<<64, 256, 0, stream>>>(w2, wt+OFF_W2, wt+OFF_W2+16384, NHID, NHID, NHID);
  prep_w<<<64, 256, 0, stream>>>(w3, wt+OFF_W3, wt+OFF_W3+16384, NHID, NHID, NHID);
  prep_w<<<8,  256, 0, stream>>>(w4, wt+OFF_W4, wt+OFF_W4+2048, NHID, NACT, 16);

  (void)hipFuncSetAttribute((const void*)dgn_main,
                            hipFuncAttributeMaxDynamicSharedMemorySize, SMEM_BYTES);
  dgn_main<<<NB, NTHR, SMEM_BYTES, stream>>>(x, mask, wt, enc_b, bv, bk, bq,
                                             b1, b2, b3, b4, out);
}

// Round 4
// 260.074 us; speedup vs baseline: 1.9055x; 1.7166x over previous
//
#include <hip/hip_runtime.h>

#define NB   1024
#define NN   128
#define NOBS 64
#define NHID 128
#define NACT 9
#define NTHR 512
#define CVS2 20   // CV row stride in dwords (80B: 16B-aligned, 2-way banks = free)

// workspace offsets (ushort elements): [hi | lo] per weight, transposed to [dout_pad][din]
#define OFF_ENC 0
#define OFF_V   16384
#define OFF_K   49152
#define OFF_Q   81920
#define OFF_W1  114688
#define OFF_W2  147456
#define OFF_W3  180224
#define OFF_W4  212992

typedef __attribute__((ext_vector_type(8))) short short8;
typedef __attribute__((ext_vector_type(4))) float f32x4;
typedef __attribute__((ext_vector_type(2))) unsigned uvec2;

union S8U { short8 s; unsigned u[4]; };

// ---------- RNE split (weights, one-time prep) ----------
__device__ __forceinline__ unsigned short bf_rne(float f){
  unsigned u = __float_as_uint(f);
  unsigned r = u + 0x7FFFu + ((u >> 16) & 1u);
  return (unsigned short)(r >> 16);
}
__device__ __forceinline__ float bf_f(unsigned short h){
  return __uint_as_float(((unsigned)h) << 16);
}
__global__ void prep_w(const float* __restrict__ w, unsigned short* __restrict__ hi,
                       unsigned short* __restrict__ lo, int din, int dout, int dpad){
  int i = blockIdx.x * blockDim.x + threadIdx.x;
  if (i >= dpad * din) return;
  int c = i / din, k = i - c * din;
  float v = (c < dout) ? w[(size_t)k * dout + c] : 0.0f;
  unsigned short h = bf_rne(v);
  unsigned short l = bf_rne(v - bf_f(h));
  hi[i] = h; lo[i] = l;
}

// ---------- fast activation split: hi = RTA-bf16 (top16), lo = rounded remainder ----------
__device__ __forceinline__ void rta_split(float f, unsigned& h, unsigned& l){
  unsigned u = __float_as_uint(f);
  h = (u + 0x8000u) & 0xFFFF0000u;
  float d = f - __uint_as_float(h);          // exact
  l = __float_as_uint(d) + 0x8000u;          // top16 = bf16 of d
}
__device__ __forceinline__ void pack_split8(const float* fv, short8& ah, short8& al){
  unsigned hu[8], lu[8];
#pragma unroll
  for (int j = 0; j < 8; ++j) rta_split(fv[j], hu[j], lu[j]);
  S8U H, L;
#pragma unroll
  for (int j = 0; j < 4; ++j){
    H.u[j] = __builtin_amdgcn_perm(hu[2*j+1], hu[2*j], 0x07060302u);
    L.u[j] = __builtin_amdgcn_perm(lu[2*j+1], lu[2*j], 0x07060302u);
  }
  ah = H.s; al = L.s;
}

// ---------- threefry2x32, key = (0, 42) ----------
__device__ __forceinline__ void tf4(unsigned& v0, unsigned& v1, int r0,int r1,int r2,int r3){
  v0 += v1; v1 = (v1<<r0)|(v1>>(32-r0)); v1 ^= v0;
  v0 += v1; v1 = (v1<<r1)|(v1>>(32-r1)); v1 ^= v0;
  v0 += v1; v1 = (v1<<r2)|(v1>>(32-r2)); v1 ^= v0;
  v0 += v1; v1 = (v1<<r3)|(v1>>(32-r3)); v1 ^= v0;
}
__device__ __forceinline__ void threefry(unsigned x0, unsigned x1, unsigned& o0, unsigned& o1){
  const unsigned ks0 = 0u, ks1 = 42u, ks2 = 0x1BD11BDAu ^ 0u ^ 42u;
  unsigned v0 = x0 + ks0, v1 = x1 + ks1;
  tf4(v0,v1,13,15,26,6);  v0 += ks1; v1 += ks2 + 1u;
  tf4(v0,v1,17,29,16,24); v0 += ks2; v1 += ks0 + 2u;
  tf4(v0,v1,13,15,26,6);  v0 += ks0; v1 += ks1 + 3u;
  tf4(v0,v1,17,29,16,24); v0 += ks1; v1 += ks2 + 4u;
  tf4(v0,v1,13,15,26,6);  v0 += ks2; v1 += ks0 + 5u;
  o0 = v0; o1 = v1;
}

#define MFMA(a,b,c) __builtin_amdgcn_mfma_f32_16x16x32_bf16((a),(b),(c),0,0,0)
#define MFMA4(ah,al,bh,bl,c) do{ (c)=MFMA((ah),(bh),(c)); (c)=MFMA((ah),(bl),(c)); \
                                 (c)=MFMA((al),(bh),(c)); (c)=MFMA((al),(bl),(c)); }while(0)

// swizzled short-index into a [rows][128]-short plane (16B-granule XOR row&7)
__device__ __forceinline__ int swzi(int row, int col){
  return row*128 + ((((col>>3) ^ (row&7)) & 15)<<3) + (col&7);
}

__device__ __forceinline__ void zero8(f32x4* a){
#pragma unroll
  for (int c = 0; c < 8; ++c) a[c] = (f32x4){0.f,0.f,0.f,0.f};
}

// cooperative stage of a weight plane-pair [ROWS][K] hi/lo from global (linear) to LDS (swizzled)
template<int ROWS, int K>
__device__ __forceinline__ void stage_w(const unsigned short* __restrict__ src,
                                        short* dsth, short* dstl, int tid){
  constexpr int GPR = K/8;
  constexpr int NG  = ROWS*GPR;
#pragma unroll
  for (int t0 = 0; t0 < NG; t0 += NTHR){
    int t = t0 + tid;
    if (NG % NTHR != 0 && t >= NG) break;
    int row = t / GPR, gc = t - row*GPR;
    int d = row*K + (((gc ^ (row & 7)) & (GPR-1))<<3);
    *(short8*)(dsth + d) = *(const short8*)(src + t*8);
    *(short8*)(dstl + d) = *(const short8*)(src + ROWS*K + t*8);
  }
}

// dense GEMM: A-frags in regs, B (weights/k/vT) in LDS swizzled [rows][K]
template<int K>
__device__ __forceinline__ void gemm_lds(const short8* fh, const short8* fl,
                                         const short* SWh, const short* SWl,
                                         f32x4* acc, int g, int l15){
  constexpr int GPR = K/8;
#pragma unroll
  for (int kp = 0; kp < K/32; ++kp){
#pragma unroll
    for (int c = 0; c < 8; ++c){
      const int row = 16*c + l15;
      const int idx = row*K + ((((4*kp + g) ^ (row & 7)) & (GPR-1))<<3);
      short8 bh = *(const short8*)(SWh + idx);
      short8 bl = *(const short8*)(SWl + idx);
      MFMA4(fh[kp], fl[kp], bh, bl, acc[c]);
    }
  }
}

// acc (C-layout) -> A-frags via per-wave CV scratch, 16-col chunks
__device__ __forceinline__ void conv_all16(const f32x4* pa, float* CVf, int g, int l15,
                                           short8* fh, short8* fl){
  const int roff = l15*CVS2 + 8*(g & 1);
#pragma unroll
  for (int kp = 0; kp < 4; ++kp){
#pragma unroll
    for (int i = 0; i < 4; ++i) CVf[(4*g+i)*CVS2 + l15] = pa[2*kp][i];
    f32x4 a0 = *(const f32x4*)(CVf + roff);
    f32x4 a1 = *(const f32x4*)(CVf + roff + 4);
#pragma unroll
    for (int i = 0; i < 4; ++i) CVf[(4*g+i)*CVS2 + l15] = pa[2*kp+1][i];
    f32x4 b0 = *(const f32x4*)(CVf + roff);
    f32x4 b1 = *(const f32x4*)(CVf + roff + 4);
    f32x4 f0 = (g < 2) ? a0 : b0;
    f32x4 f1 = (g < 2) ? a1 : b1;
    float fv[8] = {f0[0],f0[1],f0[2],f0[3],f1[0],f1[1],f1[2],f1[3]};
    pack_split8(fv, fh[kp], fl[kp]);
  }
}

__device__ __forceinline__ void finalize(f32x4* acc, const float* __restrict__ bias,
                                         int l15, bool relu){
#pragma unroll
  for (int c = 0; c < 8; ++c){
    float bb = bias[16*c + l15];
#pragma unroll
    for (int i = 0; i < 4; ++i){
      float v = acc[c][i] + bb;
      acc[c][i] = relu ? fmaxf(v, 0.0f) : v;
    }
  }
}

__global__ void __launch_bounds__(NTHR)
dgn_main(const float* __restrict__ x, const float* __restrict__ mask,
         const unsigned short* __restrict__ wt,
         const float* __restrict__ encb, const float* __restrict__ bv,
         const float* __restrict__ bk, const float* __restrict__ bq,
         const float* __restrict__ b1, const float* __restrict__ b2,
         const float* __restrict__ b3, const float* __restrict__ b4,
         float* __restrict__ out){
  // static LDS so the backend sees 75776B -> 2 blocks/CU -> 4 waves/EU -> 128-VGPR budget
  __shared__ __align__(16) short SHh[16384];
  __shared__ __align__(16) short SHl[16384];
  __shared__ __align__(16) float CVA[8*16*CVS2];

  const int tid  = threadIdx.x;
  const int lane = tid & 63;
  const int w    = tid >> 6;
  const int l15  = lane & 15;
  const int g    = lane >> 4;
  const int b    = blockIdx.x;
  float* CVf = CVA + w*16*CVS2;

  f32x4 acc[8];

  // ---- P1: h1 = relu(x @ enc_w + enc_b)
  stage_w<128, 64>(wt + OFF_ENC, SHh, SHl, tid);
  __syncthreads();                                   // enc weights ready
  zero8(acc);
  {
    short8 xh[2], xl[2];
    const float* xrow = x + ((size_t)b*NN + w*16 + l15)*NOBS;
#pragma unroll
    for (int kp = 0; kp < 2; ++kp){
      float4 f0 = *(const float4*)(xrow + 32*kp + 8*g);
      float4 f1 = *(const float4*)(xrow + 32*kp + 8*g + 4);
      float fv[8] = {f0.x,f0.y,f0.z,f0.w,f1.x,f1.y,f1.z,f1.w};
      pack_split8(fv, xh[kp], xl[kp]);
    }
    gemm_lds<NOBS>(xh, xl, SHh, SHl, acc, g, l15);
  }
  finalize(acc, encb, l15, true);
  short8 h1h[4], h1l[4];
  conv_all16(acc, CVf, g, l15, h1h, h1l);
  __syncthreads();                                   // enc reads done

  // ---- P2: q = relu(h1 @ wq + bq) -> frags in regs
  stage_w<128, 128>(wt + OFF_Q, SHh, SHl, tid);
  __syncthreads();
  zero8(acc);
  gemm_lds<NHID>(h1h, h1l, SHh, SHl, acc, g, l15);
  finalize(acc, bq, l15, true);
  short8 qfh[4], qfl[4];
  conv_all16(acc, CVf, g, l15, qfh, qfl);
  __syncthreads();                                   // Wq reads done

  // ---- P3: k = relu(h1 @ wk + bk) -> straight from acc into SH (no frag regs)
  stage_w<128, 128>(wt + OFF_K, SHh, SHl, tid);
  __syncthreads();
  zero8(acc);
  gemm_lds<NHID>(h1h, h1l, SHh, SHl, acc, g, l15);
  finalize(acc, bk, l15, true);
  __syncthreads();                                   // Wk reads done by ALL waves
#pragma unroll
  for (int c = 0; c < 8; ++c)
#pragma unroll
    for (int i = 0; i < 4; ++i){
      unsigned h, l; rta_split(acc[c][i], h, l);
      const int idx = swzi(w*16 + 4*g + i, 16*c + l15);
      SHh[idx] = (short)(h >> 16); SHl[idx] = (short)(l >> 16);
    }
  __syncthreads();                                   // k staged

  // ---- P4: scores = q @ k^T
  f32x4 sc[8];
  zero8(sc);
  gemm_lds<NHID>(qfh, qfl, SHh, SHl, sc, g, l15);
  __syncthreads();                                   // k reads done

  // ---- P5: v = relu(h1 @ wv + bv)  (h1 frags die here)
  stage_w<128, 128>(wt + OFF_V, SHh, SHl, tid);
  __syncthreads();
  zero8(acc);
  gemm_lds<NHID>(h1h, h1l, SHh, SHl, acc, g, l15);
  finalize(acc, bv, l15, true);

  // ---- P6: mask/clip -> h out, row-softmax, att -> A-frags (all in acc layout)
  short8 afh[4], afl[4];
  {
    const float* mbase = mask + (size_t)b*NN*NN;
    float* hbase = out + (size_t)NB*NN + (size_t)b*NN*NN;
    float mx[4] = {-3.0e38f,-3.0e38f,-3.0e38f,-3.0e38f};
#pragma unroll
    for (int c = 0; c < 8; ++c)
#pragma unroll
      for (int i = 0; i < 4; ++i){
        const int row = w*16 + 4*g + i, col = 16*c + l15;
        float m = mbase[row*NN + col];
        float hvv = fminf(fmaxf(sc[c][i]*m, 0.0f), 9.0e13f) - 9.0e15f*(1.0f - m);
        hbase[row*NN + col] = hvv;
        sc[c][i] = hvv;
        mx[i] = fmaxf(mx[i], hvv);
      }
#pragma unroll
    for (int off = 8; off >= 1; off >>= 1)
#pragma unroll
      for (int i = 0; i < 4; ++i) mx[i] = fmaxf(mx[i], __shfl_xor(mx[i], off, 64));
    float sm[4] = {0.f,0.f,0.f,0.f};
#pragma unroll
    for (int c = 0; c < 8; ++c)
#pragma unroll
      for (int i = 0; i < 4; ++i){
        float e = expf(sc[c][i] - mx[i]);
        sc[c][i] = e; sm[i] += e;
      }
#pragma unroll
    for (int off = 8; off >= 1; off >>= 1)
#pragma unroll
      for (int i = 0; i < 4; ++i) sm[i] += __shfl_xor(sm[i], off, 64);
    float inv[4];
#pragma unroll
    for (int i = 0; i < 4; ++i) inv[i] = 1.0f / sm[i];
#pragma unroll
    for (int c = 0; c < 8; ++c)
#pragma unroll
      for (int i = 0; i < 4; ++i) sc[c][i] *= inv[i];
    conv_all16(sc, CVf, g, l15, afh, afl);
  }
  __syncthreads();                                   // Wv reads done by all waves

  // ---- P7: stage vT (transposed, packed b64 stores)
#pragma unroll
  for (int c = 0; c < 8; ++c){
    unsigned hu[4], lu[4];
#pragma unroll
    for (int i = 0; i < 4; ++i) rta_split(acc[c][i], hu[i], lu[i]);
    uvec2 hp, lp;
    hp[0] = __builtin_amdgcn_perm(hu[1], hu[0], 0x07060302u);
    hp[1] = __builtin_amdgcn_perm(hu[3], hu[2], 0x07060302u);
    lp[0] = __builtin_amdgcn_perm(lu[1], lu[0], 0x07060302u);
    lp[1] = __builtin_amdgcn_perm(lu[3], lu[2], 0x07060302u);
    const int idx = swzi(16*c + l15, w*16 + 4*g);
    *(uvec2*)(SHh + idx) = hp;
    *(uvec2*)(SHl + idx) = lp;
  }
  __syncthreads();                                   // vT staged

  // ---- P8: h2 = att @ v
  zero8(acc);
  gemm_lds<NHID>(afh, afl, SHh, SHl, acc, g, l15);
  __syncthreads();                                   // vT reads done

  // ---- P9: MLP chain
  short8 fh[4], fl[4];
  stage_w<128, 128>(wt + OFF_W1, SHh, SHl, tid);
  conv_all16(acc, CVf, g, l15, fh, fl);              // h2 frags (no bias/relu)
  __syncthreads();
  zero8(acc);
  gemm_lds<NHID>(fh, fl, SHh, SHl, acc, g, l15);
  finalize(acc, b1, l15, true);
  __syncthreads();                                   // W1 reads done
  stage_w<128, 128>(wt + OFF_W2, SHh, SHl, tid);
  conv_all16(acc, CVf, g, l15, fh, fl);
  __syncthreads();
  zero8(acc);
  gemm_lds<NHID>(fh, fl, SHh, SHl, acc, g, l15);
  finalize(acc, b2, l15, true);
  __syncthreads();                                   // W2 reads done
  stage_w<128, 128>(wt + OFF_W3, SHh, SHl, tid);
  conv_all16(acc, CVf, g, l15, fh, fl);
  __syncthreads();
  zero8(acc);
  gemm_lds<NHID>(fh, fl, SHh, SHl, acc, g, l15);
  finalize(acc, b3, l15, true);
  __syncthreads();                                   // W3 reads done
  stage_w<16, 128>(wt + OFF_W4, SHh, SHl, tid);
  conv_all16(acc, CVf, g, l15, fh, fl);
  __syncthreads();

  // ---- P10: logits = a3 @ w4 + b4 (16-row padded weight in SH)
  f32x4 la = (f32x4){0.f,0.f,0.f,0.f};
#pragma unroll
  for (int kp = 0; kp < 4; ++kp){
    const int idx = l15*NHID + ((((4*kp + g) ^ (l15 & 7)) & 15)<<3);
    short8 bh = *(const short8*)(SHh + idx);
    short8 bl = *(const short8*)(SHl + idx);
    MFMA4(fh[kp], fl[kp], bh, bl, la);
  }
#pragma unroll
  for (int i = 0; i < 4; ++i)
    CVf[(4*g+i)*CVS2 + l15] = la[i] + ((l15 < NACT) ? b4[l15] : 0.0f);

  // ---- P11: log-softmax + threefry-gumbel + argmax (lanes g==0, one row each)
  if (g == 0){
    float lg[NACT]; float mxl = -3.0e38f;
#pragma unroll
    for (int c = 0; c < NACT; ++c){ lg[c] = CVf[l15*CVS2 + c]; mxl = fmaxf(mxl, lg[c]); }
    float s = 0.f; float p[NACT];
#pragma unroll
    for (int c = 0; c < NACT; ++c){ p[c] = expf(lg[c] - mxl); s += p[c]; }
    const int R = b*NN + w*16 + l15;
    const unsigned HHALF = (unsigned)(NB*NN*NACT/2);  // 589824
    float best = -3.0e38f; int bi = 0;
#pragma unroll
    for (int c = 0; c < NACT; ++c){
      float lp = logf(p[c] / s);
      unsigned e = (unsigned)(R*NACT + c);
      unsigned c0 = (e < HHALF) ? e : (e - HHALF);
      unsigned o0, o1; threefry(c0, c0 + HHALF, o0, o1);
      unsigned bits = (e < HHALF) ? o0 : o1;
      float u = __uint_as_float((bits >> 9) | 0x3f800000u) - 1.0f;
      float uu = fmaxf(1.17549435e-38f, u + 1.17549435e-38f);
      float gmb = -logf(-logf(uu));
      float scv = gmb + lp;
      if (scv > best){ best = scv; bi = c; }
    }
    out[R] = (float)bi;
  }
}

extern "C" void kernel_launch(void* const* d_in, const int* in_sizes, int n_in,
                              void* d_out, int out_size, void* d_ws, size_t ws_size,
                              hipStream_t stream){
  const float* x     = (const float*)d_in[0];
  const float* mask  = (const float*)d_in[1];
  const float* enc_w = (const float*)d_in[2];
  const float* enc_b = (const float*)d_in[3];
  const float* wv    = (const float*)d_in[4];
  const float* bv    = (const float*)d_in[5];
  const float* wk    = (const float*)d_in[6];
  const float* bk    = (const float*)d_in[7];
  const float* wq    = (const float*)d_in[8];
  const float* bq    = (const float*)d_in[9];
  const float* w1    = (const float*)d_in[10];
  const float* b1    = (const float*)d_in[11];
  const float* w2    = (const float*)d_in[12];
  const float* b2    = (const float*)d_in[13];
  const float* w3    = (const float*)d_in[14];
  const float* b3    = (const float*)d_in[15];
  const float* w4    = (const float*)d_in[16];
  const float* b4    = (const float*)d_in[17];
  unsigned short* wt = (unsigned short*)d_ws;
  float* out = (float*)d_out;

  prep_w<<<32, 256, 0, stream>>>(enc_w, wt+OFF_ENC, wt+OFF_ENC+8192, NOBS, NHID, NHID);
  prep_w<<<64, 256, 0, stream>>>(wv, wt+OFF_V, wt+OFF_V+16384, NHID, NHID, NHID);
  prep_w<<<64, 256, 0, stream>>>(wk, wt+OFF_K, wt+OFF_K+16384, NHID, NHID, NHID);
  prep_w<<<64, 256, 0, stream>>>(wq, wt+OFF_Q, wt+OFF_Q+16384, NHID, NHID, NHID);
  prep_w<<<64, 256, 0, stream>>>(w1, wt+OFF_W1, wt+OFF_W1+16384, NHID, NHID, NHID);
  prep_w<<<64, 256, 0, stream>>>(w2, wt+OFF_W2, wt+OFF_W2+16384, NHID, NHID, NHID);
  prep_w<<<64, 256, 0, stream>>>(w3, wt+OFF_W3, wt+OFF_W3+16384, NHID, NHID, NHID);
  prep_w<<<8,  256, 0, stream>>>(w4, wt+OFF_W4, wt+OFF_W4+2048, NHID, NACT, 16);

  dgn_main<<<NB, NTHR, 0, stream>>>(x, mask, wt, enc_b, bv, bk, bq,
                                    b1, b2, b3, b4, out);
}

// Round 5
// 195.266 us; speedup vs baseline: 2.5379x; 1.3319x over previous
//
#include <hip/hip_runtime.h>

#define NB   1024
#define NN   128
#define NOBS 64
#define NHID 128
#define NACT 9
#define NTHR 512
#define CVS2 20   // CV row stride in dwords

// workspace offsets (fp16 elements): [hi | lo] per weight, transposed to [dout_pad][din]
#define OFF_ENC 0
#define OFF_V   16384
#define OFF_K   49152
#define OFF_Q   81920
#define OFF_W1  114688
#define OFF_W2  147456
#define OFF_W3  180224
#define OFF_W4  212992

typedef __attribute__((ext_vector_type(8))) _Float16 half8;
typedef __attribute__((ext_vector_type(4))) _Float16 half4v;
typedef __attribute__((ext_vector_type(4))) float f32x4;

// ---------- weight prep: fp16 hi/lo split, transposed [dout_pad][din] ----------
__global__ void prep_w(const float* __restrict__ w, _Float16* __restrict__ hi,
                       _Float16* __restrict__ lo, int din, int dout, int dpad){
  int i = blockIdx.x * blockDim.x + threadIdx.x;
  if (i >= dpad * din) return;
  int c = i / din, k = i - c * din;
  float v = (c < dout) ? w[(size_t)k * dout + c] : 0.0f;
  _Float16 h = (_Float16)v;                 // RNE
  hi[i] = h;
  lo[i] = (_Float16)(v - (float)h);
}

// ---------- activation split: 8 f32 -> fp16 hi/lo fragments ----------
__device__ __forceinline__ void pack_split8(const float* fv, half8& ah, half8& al){
#pragma unroll
  for (int j = 0; j < 8; ++j){
    _Float16 h = (_Float16)fv[j];
    ah[j] = h;
    al[j] = (_Float16)(fv[j] - (float)h);
  }
}

// ---------- threefry2x32, key = (0, 42) ----------
__device__ __forceinline__ void tf4(unsigned& v0, unsigned& v1, int r0,int r1,int r2,int r3){
  v0 += v1; v1 = (v1<<r0)|(v1>>(32-r0)); v1 ^= v0;
  v0 += v1; v1 = (v1<<r1)|(v1>>(32-r1)); v1 ^= v0;
  v0 += v1; v1 = (v1<<r2)|(v1>>(32-r2)); v1 ^= v0;
  v0 += v1; v1 = (v1<<r3)|(v1>>(32-r3)); v1 ^= v0;
}
__device__ __forceinline__ void threefry(unsigned x0, unsigned x1, unsigned& o0, unsigned& o1){
  const unsigned ks0 = 0u, ks1 = 42u, ks2 = 0x1BD11BDAu ^ 0u ^ 42u;
  unsigned v0 = x0 + ks0, v1 = x1 + ks1;
  tf4(v0,v1,13,15,26,6);  v0 += ks1; v1 += ks2 + 1u;
  tf4(v0,v1,17,29,16,24); v0 += ks2; v1 += ks0 + 2u;
  tf4(v0,v1,13,15,26,6);  v0 += ks0; v1 += ks1 + 3u;
  tf4(v0,v1,17,29,16,24); v0 += ks1; v1 += ks2 + 4u;
  tf4(v0,v1,13,15,26,6);  v0 += ks2; v1 += ks0 + 5u;
  o0 = v0; o1 = v1;
}

#define MFMA(a,b,c) __builtin_amdgcn_mfma_f32_16x16x32_f16((a),(b),(c),0,0,0)
// 3-term split product: ah*bh + al*bh + ah*bl  (al*bl ~ 2^-22, omitted)
#define MFMA3(ah,al,bh,bl,c) do{ (c)=MFMA((ah),(bh),(c)); (c)=MFMA((al),(bh),(c)); \
                                 (c)=MFMA((ah),(bl),(c)); }while(0)

// swizzled element-index into a [rows][128]-half plane (8-elem-granule XOR row&7)
__device__ __forceinline__ int swzi(int row, int col){
  return row*128 + ((((col>>3) ^ (row&7)) & 15)<<3) + (col&7);
}

__device__ __forceinline__ void zero8(f32x4* a){
#pragma unroll
  for (int c = 0; c < 8; ++c) a[c] = (f32x4){0.f,0.f,0.f,0.f};
}

// ---------- direct stage: global (linear) -> LDS (swizzled) ----------
template<int ROWS, int K>
__device__ __forceinline__ void stage_w(const _Float16* __restrict__ src,
                                        _Float16* dsth, _Float16* dstl, int tid){
  constexpr int GPR = K/8;
  constexpr int NG  = ROWS*GPR;
#pragma unroll
  for (int t0 = 0; t0 < NG; t0 += NTHR){
    int t = t0 + tid;
    if (NG % NTHR != 0 && t >= NG) break;
    int row = t / GPR, gc = t - row*GPR;
    int d = row*K + (((gc ^ (row & 7)) & (GPR-1))<<3);
    *(half8*)(dsth + d) = *(const half8*)(src + t*8);
    *(half8*)(dstl + d) = *(const half8*)(src + ROWS*K + t*8);
  }
}

// ---------- async stage: issue global->reg early, write reg->LDS after barrier ----------
template<int NG>
__device__ __forceinline__ void stage_load(const _Float16* __restrict__ src, int loOff,
                                           half8* bh, half8* bl, int tid){
#pragma unroll
  for (int j = 0; j*NTHR < NG; ++j){
    int t = j*NTHR + tid;
    if (NG % NTHR != 0 && t >= NG) break;
    bh[j] = *(const half8*)(src + t*8);
    bl[j] = *(const half8*)(src + loOff + t*8);
  }
}
template<int NG, int GPR>
__device__ __forceinline__ void stage_write(const half8* bh, const half8* bl,
                                            _Float16* dsth, _Float16* dstl, int tid){
#pragma unroll
  for (int j = 0; j*NTHR < NG; ++j){
    int t = j*NTHR + tid;
    if (NG % NTHR != 0 && t >= NG) break;
    int row = t / GPR, gc = t - row*GPR;
    int d = row*(GPR*8) + (((gc ^ (row & 7)) & (GPR-1))<<3);
    *(half8*)(dsth + d) = bh[j];
    *(half8*)(dstl + d) = bl[j];
  }
}

// dense GEMM: A-frags in regs, B in LDS swizzled [rows][K] hi/lo
template<int K>
__device__ __forceinline__ void gemm_lds(const half8* fh, const half8* fl,
                                         const _Float16* SWh, const _Float16* SWl,
                                         f32x4* acc, int g, int l15){
  constexpr int GPR = K/8;
#pragma unroll
  for (int kp = 0; kp < K/32; ++kp){
#pragma unroll
    for (int c = 0; c < 8; ++c){
      const int row = 16*c + l15;
      const int idx = row*K + ((((4*kp + g) ^ (row & 7)) & (GPR-1))<<3);
      half8 bh = *(const half8*)(SWh + idx);
      half8 bl = *(const half8*)(SWl + idx);
      MFMA3(fh[kp], fl[kp], bh, bl, acc[c]);
    }
  }
}

// acc (C-layout) -> A-frags via per-wave CV scratch, 16-col chunks
__device__ __forceinline__ void conv_all16(const f32x4* pa, float* CVf, int g, int l15,
                                           half8* fh, half8* fl){
  const int roff = l15*CVS2 + 8*(g & 1);
#pragma unroll
  for (int kp = 0; kp < 4; ++kp){
#pragma unroll
    for (int i = 0; i < 4; ++i) CVf[(4*g+i)*CVS2 + l15] = pa[2*kp][i];
    f32x4 a0 = *(const f32x4*)(CVf + roff);
    f32x4 a1 = *(const f32x4*)(CVf + roff + 4);
#pragma unroll
    for (int i = 0; i < 4; ++i) CVf[(4*g+i)*CVS2 + l15] = pa[2*kp+1][i];
    f32x4 b0 = *(const f32x4*)(CVf + roff);
    f32x4 b1 = *(const f32x4*)(CVf + roff + 4);
    f32x4 f0 = (g < 2) ? a0 : b0;
    f32x4 f1 = (g < 2) ? a1 : b1;
    float fv[8] = {f0[0],f0[1],f0[2],f0[3],f1[0],f1[1],f1[2],f1[3]};
    pack_split8(fv, fh[kp], fl[kp]);
  }
}

__device__ __forceinline__ void finalize(f32x4* acc, const float* __restrict__ bias,
                                         int l15, bool relu){
#pragma unroll
  for (int c = 0; c < 8; ++c){
    float bb = bias[16*c + l15];
#pragma unroll
    for (int i = 0; i < 4; ++i){
      float v = acc[c][i] + bb;
      acc[c][i] = relu ? fmaxf(v, 0.0f) : v;
    }
  }
}

__global__ void __launch_bounds__(NTHR)
dgn_main(const float* __restrict__ x, const float* __restrict__ mask,
         const _Float16* __restrict__ wt,
         const float* __restrict__ encb, const float* __restrict__ bv,
         const float* __restrict__ bk, const float* __restrict__ bq,
         const float* __restrict__ b1, const float* __restrict__ b2,
         const float* __restrict__ b3, const float* __restrict__ b4,
         float* __restrict__ out){
  // static LDS: 2 blocks/CU -> 16 waves/CU, VGPR cap 128
  __shared__ __align__(16) _Float16 SHh[16384];
  __shared__ __align__(16) _Float16 SHl[16384];
  __shared__ __align__(16) float CVA[8*16*CVS2];

  const int tid  = threadIdx.x;
  const int lane = tid & 63;
  const int w    = tid >> 6;
  const int l15  = lane & 15;
  const int g    = lane >> 4;
  const int b    = blockIdx.x;
  float* CVf = CVA + w*16*CVS2;

  f32x4 acc[8];
  half8 wbh[4], wbl[4];   // async weight staging buffer (32 VGPR)

  // ---- P0: direct stage enc weights
  stage_w<128, 64>(wt + OFF_ENC, SHh, SHl, tid);
  __syncthreads();

  // ---- P1: h1 = relu(x @ enc_w + enc_b); prefetch Wq
  stage_load<2048>(wt + OFF_Q, 16384, wbh, wbl, tid);
  zero8(acc);
  {
    half8 xh[2], xl[2];
    const float* xrow = x + ((size_t)b*NN + w*16 + l15)*NOBS;
#pragma unroll
    for (int kp = 0; kp < 2; ++kp){
      float4 f0 = *(const float4*)(xrow + 32*kp + 8*g);
      float4 f1 = *(const float4*)(xrow + 32*kp + 8*g + 4);
      float fv[8] = {f0.x,f0.y,f0.z,f0.w,f1.x,f1.y,f1.z,f1.w};
      pack_split8(fv, xh[kp], xl[kp]);
    }
    gemm_lds<NOBS>(xh, xl, SHh, SHl, acc, g, l15);
  }
  finalize(acc, encb, l15, true);
  half8 h1h[4], h1l[4];
  conv_all16(acc, CVf, g, l15, h1h, h1l);
  __syncthreads();                       // enc reads done
  stage_write<2048,16>(wbh, wbl, SHh, SHl, tid);
  __syncthreads();                       // Wq staged

  // ---- P2: q = relu(h1 @ wq + bq); prefetch Wk
  stage_load<2048>(wt + OFF_K, 16384, wbh, wbl, tid);
  zero8(acc);
  gemm_lds<NHID>(h1h, h1l, SHh, SHl, acc, g, l15);
  finalize(acc, bq, l15, true);
  half8 qfh[4], qfl[4];
  conv_all16(acc, CVf, g, l15, qfh, qfl);
  __syncthreads();                       // Wq reads done
  stage_write<2048,16>(wbh, wbl, SHh, SHl, tid);
  __syncthreads();                       // Wk staged

  // ---- P3: k = relu(h1 @ wk + bk) -> straight from acc into SH
  zero8(acc);
  gemm_lds<NHID>(h1h, h1l, SHh, SHl, acc, g, l15);
  finalize(acc, bk, l15, true);
  __syncthreads();                       // Wk reads done by ALL waves
#pragma unroll
  for (int c = 0; c < 8; ++c)
#pragma unroll
    for (int i = 0; i < 4; ++i){
      float v = acc[c][i];
      _Float16 kh = (_Float16)v;
      const int idx = swzi(w*16 + 4*g + i, 16*c + l15);
      SHh[idx] = kh;
      SHl[idx] = (_Float16)(v - (float)kh);
    }
  __syncthreads();                       // k staged

  // ---- P4: scores = q @ k^T
  f32x4 sc[8];
  zero8(sc);
  gemm_lds<NHID>(qfh, qfl, SHh, SHl, sc, g, l15);
  __syncthreads();                       // k reads done

  // ---- P5: stage Wv direct; v = relu(h1 @ wv + bv)
  stage_w<128, 128>(wt + OFF_V, SHh, SHl, tid);
  __syncthreads();
  zero8(acc);
  gemm_lds<NHID>(h1h, h1l, SHh, SHl, acc, g, l15);
  finalize(acc, bv, l15, true);

  // ---- P6: mask/clip -> h out, row-softmax, att (scaled 2^14) -> A-frags
  half8 afh[4], afl[4];
  {
    const float* mbase = mask + (size_t)b*NN*NN;
    float* hbase = out + (size_t)NB*NN + (size_t)b*NN*NN;
    float mx[4] = {-3.0e38f,-3.0e38f,-3.0e38f,-3.0e38f};
#pragma unroll
    for (int c = 0; c < 8; ++c)
#pragma unroll
      for (int i = 0; i < 4; ++i){
        const int row = w*16 + 4*g + i, col = 16*c + l15;
        float m = mbase[row*NN + col];
        float hvv = fminf(fmaxf(sc[c][i]*m, 0.0f), 9.0e13f) - 9.0e15f*(1.0f - m);
        hbase[row*NN + col] = hvv;
        sc[c][i] = hvv;
        mx[i] = fmaxf(mx[i], hvv);
      }
#pragma unroll
    for (int off = 8; off >= 1; off >>= 1)
#pragma unroll
      for (int i = 0; i < 4; ++i) mx[i] = fmaxf(mx[i], __shfl_xor(mx[i], off, 64));
    float sm[4] = {0.f,0.f,0.f,0.f};
#pragma unroll
    for (int c = 0; c < 8; ++c)
#pragma unroll
      for (int i = 0; i < 4; ++i){
        float e = expf(sc[c][i] - mx[i]);
        sc[c][i] = e; sm[i] += e;
      }
#pragma unroll
    for (int off = 8; off >= 1; off >>= 1)
#pragma unroll
      for (int i = 0; i < 4; ++i) sm[i] += __shfl_xor(sm[i], off, 64);
    float inv[4];
#pragma unroll
    for (int i = 0; i < 4; ++i) inv[i] = 16384.0f / sm[i];   // 2^14 denorm-guard scale
#pragma unroll
    for (int c = 0; c < 8; ++c)
#pragma unroll
      for (int i = 0; i < 4; ++i) sc[c][i] *= inv[i];
    conv_all16(sc, CVf, g, l15, afh, afl);
  }
  __syncthreads();                       // Wv reads done by all waves

  // ---- P7: stage vT (transposed, packed b64 stores)
#pragma unroll
  for (int c = 0; c < 8; ++c){
    half4v hp, lp;
#pragma unroll
    for (int i = 0; i < 4; ++i){
      float v = acc[c][i];
      _Float16 hh = (_Float16)v;
      hp[i] = hh;
      lp[i] = (_Float16)(v - (float)hh);
    }
    const int idx = swzi(16*c + l15, w*16 + 4*g);
    *(half4v*)(SHh + idx) = hp;
    *(half4v*)(SHl + idx) = lp;
  }
  __syncthreads();                       // vT staged

  // ---- P8: h2 = att @ v (scaled); prefetch W1
  stage_load<2048>(wt + OFF_W1, 16384, wbh, wbl, tid);
  zero8(acc);
  gemm_lds<NHID>(afh, afl, SHh, SHl, acc, g, l15);
#pragma unroll
  for (int c = 0; c < 8; ++c)
#pragma unroll
    for (int i = 0; i < 4; ++i) acc[c][i] *= 6.103515625e-05f;  // 2^-14
  half8 fh[4], fl[4];
  conv_all16(acc, CVf, g, l15, fh, fl);
  __syncthreads();                       // vT reads done
  stage_write<2048,16>(wbh, wbl, SHh, SHl, tid);
  __syncthreads();                       // W1 staged

  // ---- P9: MLP chain with async staging
  stage_load<2048>(wt + OFF_W2, 16384, wbh, wbl, tid);
  zero8(acc);
  gemm_lds<NHID>(fh, fl, SHh, SHl, acc, g, l15);
  finalize(acc, b1, l15, true);
  conv_all16(acc, CVf, g, l15, fh, fl);
  __syncthreads();                       // W1 reads done
  stage_write<2048,16>(wbh, wbl, SHh, SHl, tid);
  __syncthreads();                       // W2 staged

  stage_load<2048>(wt + OFF_W3, 16384, wbh, wbl, tid);
  zero8(acc);
  gemm_lds<NHID>(fh, fl, SHh, SHl, acc, g, l15);
  finalize(acc, b2, l15, true);
  conv_all16(acc, CVf, g, l15, fh, fl);
  __syncthreads();                       // W2 reads done
  stage_write<2048,16>(wbh, wbl, SHh, SHl, tid);
  __syncthreads();                       // W3 staged

  stage_load<256>(wt + OFF_W4, 2048, wbh, wbl, tid);
  zero8(acc);
  gemm_lds<NHID>(fh, fl, SHh, SHl, acc, g, l15);
  finalize(acc, b3, l15, true);
  conv_all16(acc, CVf, g, l15, fh, fl);
  __syncthreads();                       // W3 reads done
  stage_write<256,16>(wbh, wbl, SHh, SHl, tid);
  __syncthreads();                       // W4 staged

  // ---- P10: logits = a3 @ w4 + b4 (16-row padded weight in SH)
  f32x4 la = (f32x4){0.f,0.f,0.f,0.f};
#pragma unroll
  for (int kp = 0; kp < 4; ++kp){
    const int idx = l15*NHID + ((((4*kp + g) ^ (l15 & 7)) & 15)<<3);
    half8 bh = *(const half8*)(SHh + idx);
    half8 bl = *(const half8*)(SHl + idx);
    MFMA3(fh[kp], fl[kp], bh, bl, la);
  }
#pragma unroll
  for (int i = 0; i < 4; ++i)
    CVf[(4*g+i)*CVS2 + l15] = la[i] + ((l15 < NACT) ? b4[l15] : 0.0f);

  // ---- P11: log-softmax + threefry-gumbel + argmax (lanes g==0, one row each)
  if (g == 0){
    float lg[NACT]; float mxl = -3.0e38f;
#pragma unroll
    for (int c = 0; c < NACT; ++c){ lg[c] = CVf[l15*CVS2 + c]; mxl = fmaxf(mxl, lg[c]); }
    float s = 0.f; float p[NACT];
#pragma unroll
    for (int c = 0; c < NACT; ++c){ p[c] = expf(lg[c] - mxl); s += p[c]; }
    const int R = b*NN + w*16 + l15;
    const unsigned HHALF = (unsigned)(NB*NN*NACT/2);  // 589824
    float best = -3.0e38f; int bi = 0;
#pragma unroll
    for (int c = 0; c < NACT; ++c){
      float lp = logf(p[c] / s);
      unsigned e = (unsigned)(R*NACT + c);
      unsigned c0 = (e < HHALF) ? e : (e - HHALF);
      unsigned o0, o1; threefry(c0, c0 + HHALF, o0, o1);
      unsigned bits = (e < HHALF) ? o0 : o1;
      float u = __uint_as_float((bits >> 9) | 0x3f800000u) - 1.0f;
      float uu = fmaxf(1.17549435e-38f, u + 1.17549435e-38f);
      float gmb = -logf(-logf(uu));
      float scv = gmb + lp;
      if (scv > best){ best = scv; bi = c; }
    }
    out[R] = (float)bi;
  }
}

extern "C" void kernel_launch(void* const* d_in, const int* in_sizes, int n_in,
                              void* d_out, int out_size, void* d_ws, size_t ws_size,
                              hipStream_t stream){
  const float* x     = (const float*)d_in[0];
  const float* mask  = (const float*)d_in[1];
  const float* enc_w = (const float*)d_in[2];
  const float* enc_b = (const float*)d_in[3];
  const float* wv    = (const float*)d_in[4];
  const float* bv    = (const float*)d_in[5];
  const float* wk    = (const float*)d_in[6];
  const float* bk    = (const float*)d_in[7];
  const float* wq    = (const float*)d_in[8];
  const float* bq    = (const float*)d_in[9];
  const float* w1    = (const float*)d_in[10];
  const float* b1    = (const float*)d_in[11];
  const float* w2    = (const float*)d_in[12];
  const float* b2    = (const float*)d_in[13];
  const float* w3    = (const float*)d_in[14];
  const float* b3    = (const float*)d_in[15];
  const float* w4    = (const float*)d_in[16];
  const float* b4    = (const float*)d_in[17];
  _Float16* wt = (_Float16*)d_ws;
  float* out = (float*)d_out;

  prep_w<<<32, 256, 0, stream>>>(enc_w, wt+OFF_ENC, wt+OFF_ENC+8192, NOBS, NHID, NHID);
  prep_w<<<64, 256, 0, stream>>>(wv, wt+OFF_V, wt+OFF_V+16384, NHID, NHID, NHID);
  prep_w<<<64, 256, 0, stream>>>(wk, wt+OFF_K, wt+OFF_K+16384, NHID, NHID, NHID);
  prep_w<<<64, 256, 0, stream>>>(wq, wt+OFF_Q, wt+OFF_Q+16384, NHID, NHID, NHID);
  prep_w<<<64, 256, 0, stream>>>(w1, wt+OFF_W1, wt+OFF_W1+16384, NHID, NHID, NHID);
  prep_w<<<64, 256, 0, stream>>>(w2, wt+OFF_W2, wt+OFF_W2+16384, NHID, NHID, NHID);
  prep_w<<<64, 256, 0, stream>>>(w3, wt+OFF_W3, wt+OFF_W3+16384, NHID, NHID, NHID);
  prep_w<<<8,  256, 0, stream>>>(w4, wt+OFF_W4, wt+OFF_W4+2048, NHID, NACT, 16);

  dgn_main<<<NB, NTHR, 0, stream>>>(x, mask, wt, enc_b, bv, bk, bq,
                                    b1, b2, b3, b4, out);
}

// Round 7
// 187.011 us; speedup vs baseline: 2.6499x; 1.0441x over previous
//
#include <hip/hip_runtime.h>

#define NB   1024
#define NN   128
#define NOBS 64
#define NHID 128
#define NACT 9
#define NTHR 512
#define WLD  136   // padded LDS row stride in halves: conflict-free b128 column reads
#define CVS2 20    // CV row stride in dwords

// workspace offsets (fp16 elements): [hi | lo] per weight, transposed to [dout_pad][din]
#define OFF_ENC 0
#define OFF_V   16384
#define OFF_K   49152
#define OFF_Q   81920
#define OFF_W1  114688
#define OFF_W2  147456
#define OFF_W3  180224
#define OFF_W4  212992

typedef __attribute__((ext_vector_type(8))) _Float16 half8;
typedef __attribute__((ext_vector_type(4))) _Float16 half4v;
typedef __attribute__((ext_vector_type(2))) __fp16 fp16x2;
typedef __attribute__((ext_vector_type(4))) float f32x4;

union H8 { half8 v; fp16x2 p[4]; };
union H4 { half4v v; fp16x2 p[2]; };

// ---------- weight prep: fp16 hi/lo split (RNE), transposed [dout_pad][din] ----------
__global__ void prep_w(const float* __restrict__ w, _Float16* __restrict__ hi,
                       _Float16* __restrict__ lo, int din, int dout, int dpad){
  int i = blockIdx.x * blockDim.x + threadIdx.x;
  if (i >= dpad * din) return;
  int c = i / din, k = i - c * din;
  float v = (c < dout) ? w[(size_t)k * dout + c] : 0.0f;
  _Float16 h = (_Float16)v;
  hi[i] = h;
  lo[i] = (_Float16)(v - (float)h);
}

// ---------- activation split: 8 f32 -> fp16 hi/lo fragments via packed RTZ converts ----------
__device__ __forceinline__ void pack_split8(const float* fv, half8& ah, half8& al){
  H8 A, L;
#pragma unroll
  for (int j = 0; j < 4; ++j){
    fp16x2 h = __builtin_amdgcn_cvt_pkrtz(fv[2*j], fv[2*j+1]);
    float r0 = fv[2*j]   - (float)h[0];
    float r1 = fv[2*j+1] - (float)h[1];
    A.p[j] = h;
    L.p[j] = __builtin_amdgcn_cvt_pkrtz(r0, r1);
  }
  ah = A.v; al = L.v;
}

// ---------- threefry2x32, key = (0, 42) ----------
__device__ __forceinline__ void tf4(unsigned& v0, unsigned& v1, int r0,int r1,int r2,int r3){
  v0 += v1; v1 = (v1<<r0)|(v1>>(32-r0)); v1 ^= v0;
  v0 += v1; v1 = (v1<<r1)|(v1>>(32-r1)); v1 ^= v0;
  v0 += v1; v1 = (v1<<r2)|(v1>>(32-r2)); v1 ^= v0;
  v0 += v1; v1 = (v1<<r3)|(v1>>(32-r3)); v1 ^= v0;
}
__device__ __forceinline__ void threefry(unsigned x0, unsigned x1, unsigned& o0, unsigned& o1){
  const unsigned ks0 = 0u, ks1 = 42u, ks2 = 0x1BD11BDAu ^ 0u ^ 42u;
  unsigned v0 = x0 + ks0, v1 = x1 + ks1;
  tf4(v0,v1,13,15,26,6);  v0 += ks1; v1 += ks2 + 1u;
  tf4(v0,v1,17,29,16,24); v0 += ks2; v1 += ks0 + 2u;
  tf4(v0,v1,13,15,26,6);  v0 += ks0; v1 += ks1 + 3u;
  tf4(v0,v1,17,29,16,24); v0 += ks1; v1 += ks2 + 4u;
  tf4(v0,v1,13,15,26,6);  v0 += ks2; v1 += ks0 + 5u;
  o0 = v0; o1 = v1;
}

#define MFMA(a,b,c) __builtin_amdgcn_mfma_f32_16x16x32_f16((a),(b),(c),0,0,0)
// 3-term split product: ah*bh + al*bh + ah*bl  (al*bl ~ 2^-22, omitted)
#define MFMA3(ah,al,bh,bl,c) do{ (c)=MFMA((ah),(bh),(c)); (c)=MFMA((al),(bh),(c)); \
                                 (c)=MFMA((ah),(bl),(c)); }while(0)

__device__ __forceinline__ void zero8(f32x4* a){
#pragma unroll
  for (int c = 0; c < 8; ++c) a[c] = (f32x4){0.f,0.f,0.f,0.f};
}

// ---------- direct stage: global (linear) -> LDS (padded rows, linear granules) ----------
template<int ROWS, int K>
__device__ __forceinline__ void stage_w(const _Float16* __restrict__ src,
                                        _Float16* dsth, _Float16* dstl, int tid){
  constexpr int GPR = K/8;
  constexpr int NG  = ROWS*GPR;
#pragma unroll
  for (int t0 = 0; t0 < NG; t0 += NTHR){
    int t = t0 + tid;
    if (NG % NTHR != 0 && t >= NG) break;
    int row = t / GPR, gc = t - row*GPR;
    int d = row*WLD + gc*8;
    *(half8*)(dsth + d) = *(const half8*)(src + t*8);
    *(half8*)(dstl + d) = *(const half8*)(src + ROWS*K + t*8);
  }
}

// ---------- async stage: issue global->reg early, write reg->LDS after barrier ----------
template<int NG>
__device__ __forceinline__ void stage_load(const _Float16* __restrict__ src, int loOff,
                                           half8* bh, half8* bl, int tid){
#pragma unroll
  for (int j = 0; j*NTHR < NG; ++j){
    int t = j*NTHR + tid;
    if (NG % NTHR != 0 && t >= NG) break;
    bh[j] = *(const half8*)(src + t*8);
    bl[j] = *(const half8*)(src + loOff + t*8);
  }
}
template<int NG, int GPR>
__device__ __forceinline__ void stage_write(const half8* bh, const half8* bl,
                                            _Float16* dsth, _Float16* dstl, int tid){
#pragma unroll
  for (int j = 0; j*NTHR < NG; ++j){
    int t = j*NTHR + tid;
    if (NG % NTHR != 0 && t >= NG) break;
    int row = t / GPR, gc = t - row*GPR;
    int d = row*WLD + gc*8;
    *(half8*)(dsth + d) = bh[j];
    *(half8*)(dstl + d) = bl[j];
  }
}

// dense GEMM: A-frags in regs, B in LDS padded [rows][WLD] hi/lo
template<int K>
__device__ __forceinline__ void gemm_lds(const half8* fh, const half8* fl,
                                         const _Float16* SWh, const _Float16* SWl,
                                         f32x4* acc, int g, int l15){
#pragma unroll
  for (int kp = 0; kp < K/32; ++kp){
#pragma unroll
    for (int c = 0; c < 8; ++c){
      const int idx = (16*c + l15)*WLD + (4*kp + g)*8;
      half8 bh = *(const half8*)(SWh + idx);
      half8 bl = *(const half8*)(SWl + idx);
      MFMA3(fh[kp], fl[kp], bh, bl, acc[c]);
    }
  }
}

// acc chunk kp -> this lane's row-major 8 f32 (row l15, cols 8g..8g+7) via wave-private CV
__device__ __forceinline__ void cv_row8(const f32x4* pa, int kp, float* CVf,
                                        int g, int l15, float* fv){
  const int roff = l15*CVS2 + 8*(g & 1);
#pragma unroll
  for (int i = 0; i < 4; ++i) CVf[(4*g+i)*CVS2 + l15] = pa[2*kp][i];
  f32x4 a0 = *(const f32x4*)(CVf + roff);
  f32x4 a1 = *(const f32x4*)(CVf + roff + 4);
#pragma unroll
  for (int i = 0; i < 4; ++i) CVf[(4*g+i)*CVS2 + l15] = pa[2*kp+1][i];
  f32x4 b0 = *(const f32x4*)(CVf + roff);
  f32x4 b1 = *(const f32x4*)(CVf + roff + 4);
  f32x4 f0 = (g < 2) ? a0 : b0;
  f32x4 f1 = (g < 2) ? a1 : b1;
  fv[0]=f0[0]; fv[1]=f0[1]; fv[2]=f0[2]; fv[3]=f0[3];
  fv[4]=f1[0]; fv[5]=f1[1]; fv[6]=f1[2]; fv[7]=f1[3];
}

// full acc -> 4 fragment pairs
__device__ __forceinline__ void conv_all16(const f32x4* pa, float* CVf, int g, int l15,
                                           half8* fh, half8* fl){
#pragma unroll
  for (int kp = 0; kp < 4; ++kp){
    float fv[8];
    cv_row8(pa, kp, CVf, g, l15, fv);
    pack_split8(fv, fh[kp], fl[kp]);
  }
}

// fused conv + GEMM: per kp, convert A chunk then immediately run its 24 MFMAs
__device__ __forceinline__ void gemm_cv(const f32x4* pa, float* CVf,
                                        const _Float16* SWh, const _Float16* SWl,
                                        f32x4* acc, int g, int l15){
#pragma unroll
  for (int kp = 0; kp < 4; ++kp){
    float fv[8];
    cv_row8(pa, kp, CVf, g, l15, fv);
    half8 ah, al;
    pack_split8(fv, ah, al);
#pragma unroll
    for (int c = 0; c < 8; ++c){
      const int idx = (16*c + l15)*WLD + (4*kp + g)*8;
      half8 bh = *(const half8*)(SWh + idx);
      half8 bl = *(const half8*)(SWl + idx);
      MFMA3(ah, al, bh, bl, acc[c]);
    }
  }
}

__device__ __forceinline__ void finalize(f32x4* acc, const float* __restrict__ bias,
                                         int l15, bool relu){
#pragma unroll
  for (int c = 0; c < 8; ++c){
    float bb = bias[16*c + l15];
#pragma unroll
    for (int i = 0; i < 4; ++i){
      float v = acc[c][i] + bb;
      acc[c][i] = relu ? fmaxf(v, 0.0f) : v;
    }
  }
}

__global__ void __launch_bounds__(NTHR)
dgn_main(const float* __restrict__ x, const float* __restrict__ mask,
         const _Float16* __restrict__ wt,
         const float* __restrict__ encb, const float* __restrict__ bv,
         const float* __restrict__ bk, const float* __restrict__ bq,
         const float* __restrict__ b1, const float* __restrict__ b2,
         const float* __restrict__ b3, const float* __restrict__ b4,
         float* __restrict__ out){
  // static LDS: 2*34816 + 10240 = 79872 B -> 2 blocks/CU, VGPR cap 128
  __shared__ __align__(16) _Float16 SHh[128*WLD];
  __shared__ __align__(16) _Float16 SHl[128*WLD];
  __shared__ __align__(16) float CVA[8*16*CVS2];

  const int tid  = threadIdx.x;
  const int lane = tid & 63;
  const int w    = tid >> 6;
  const int l15  = lane & 15;
  const int g    = lane >> 4;
  const int b    = blockIdx.x;
  float* CVf = CVA + w*16*CVS2;

  f32x4 accA[8], accB[8];
  half8 wbh[4], wbl[4];   // async weight staging buffer (32 VGPR)

  // ---- P0: direct stage enc weights
  stage_w<128, 64>(wt + OFF_ENC, SHh, SHl, tid);
  __syncthreads();                                   // B1 enc ready

  // ---- P1: h1 = relu(x @ enc_w + enc_b); prefetch Wq
  stage_load<2048>(wt + OFF_Q, 16384, wbh, wbl, tid);
  zero8(accA);
  {
    half8 xh[2], xl[2];
    const float* xrow = x + ((size_t)b*NN + w*16 + l15)*NOBS;
#pragma unroll
    for (int kp = 0; kp < 2; ++kp){
      float4 f0 = *(const float4*)(xrow + 32*kp + 8*g);
      float4 f1 = *(const float4*)(xrow + 32*kp + 8*g + 4);
      float fv[8] = {f0.x,f0.y,f0.z,f0.w,f1.x,f1.y,f1.z,f1.w};
      pack_split8(fv, xh[kp], xl[kp]);
    }
    gemm_lds<NOBS>(xh, xl, SHh, SHl, accA, g, l15);
  }
  finalize(accA, encb, l15, true);
  __syncthreads();                                   // B2 enc reads done
  stage_write<2048,16>(wbh, wbl, SHh, SHl, tid);
  __syncthreads();                                   // B3 Wq ready
  half8 h1h[4], h1l[4];
  conv_all16(accA, CVf, g, l15, h1h, h1l);

  // ---- P2: q = relu(h1 @ wq + bq); prefetch Wk
  stage_load<2048>(wt + OFF_K, 16384, wbh, wbl, tid);
  zero8(accA);
  gemm_lds<NHID>(h1h, h1l, SHh, SHl, accA, g, l15);
  finalize(accA, bq, l15, true);
  __syncthreads();                                   // B4 Wq reads done
  stage_write<2048,16>(wbh, wbl, SHh, SHl, tid);
  __syncthreads();                                   // B5 Wk ready
  half8 qfh[4], qfl[4];
  conv_all16(accA, CVf, g, l15, qfh, qfl);

  // ---- P3: k = relu(h1 @ wk + bk) -> split straight into SH
  zero8(accA);
  gemm_lds<NHID>(h1h, h1l, SHh, SHl, accA, g, l15);
  finalize(accA, bk, l15, true);
  __syncthreads();                                   // B6 Wk reads done (all waves)
#pragma unroll
  for (int c = 0; c < 8; ++c)
#pragma unroll
    for (int i = 0; i < 4; ++i){
      float v = accA[c][i];
      _Float16 kh = (_Float16)v;
      const int idx = (w*16 + 4*g + i)*WLD + 16*c + l15;
      SHh[idx] = kh;
      SHl[idx] = (_Float16)(v - (float)kh);
    }
  __syncthreads();                                   // B7 k staged

  // ---- P4: scores = q @ k^T
  zero8(accB);
  gemm_lds<NHID>(qfh, qfl, SHh, SHl, accB, g, l15);
  __syncthreads();                                   // B8 k reads done

  // ---- P5: mask/clip -> h out, row-softmax (acc layout), att frags; Wv prefetched under it
  stage_load<2048>(wt + OFF_V, 16384, wbh, wbl, tid);
  half8 afh[4], afl[4];
  {
    const float* mbase = mask + (size_t)b*NN*NN;
    float* hbase = out + (size_t)NB*NN + (size_t)b*NN*NN;
    float mx[4] = {-3.0e38f,-3.0e38f,-3.0e38f,-3.0e38f};
#pragma unroll
    for (int c = 0; c < 8; ++c)
#pragma unroll
      for (int i = 0; i < 4; ++i){
        const int row = w*16 + 4*g + i, col = 16*c + l15;
        float m = mbase[row*NN + col];
        float hvv = fminf(fmaxf(accB[c][i]*m, 0.0f), 9.0e13f) - 9.0e15f*(1.0f - m);
        hbase[row*NN + col] = hvv;
        accB[c][i] = hvv;
        mx[i] = fmaxf(mx[i], hvv);
      }
#pragma unroll
    for (int off = 8; off >= 1; off >>= 1)
#pragma unroll
      for (int i = 0; i < 4; ++i) mx[i] = fmaxf(mx[i], __shfl_xor(mx[i], off, 64));
    float sm[4] = {0.f,0.f,0.f,0.f};
#pragma unroll
    for (int c = 0; c < 8; ++c)
#pragma unroll
      for (int i = 0; i < 4; ++i){
        float e = __expf(accB[c][i] - mx[i]);
        accB[c][i] = e; sm[i] += e;
      }
#pragma unroll
    for (int off = 8; off >= 1; off >>= 1)
#pragma unroll
      for (int i = 0; i < 4; ++i) sm[i] += __shfl_xor(sm[i], off, 64);
    float inv[4];
#pragma unroll
    for (int i = 0; i < 4; ++i) inv[i] = 16384.0f / sm[i];  // 2^14 denorm guard
#pragma unroll
    for (int c = 0; c < 8; ++c)
#pragma unroll
      for (int i = 0; i < 4; ++i) accB[c][i] *= inv[i];
    conv_all16(accB, CVf, g, l15, afh, afl);
  }
  stage_write<2048,16>(wbh, wbl, SHh, SHl, tid);
  __syncthreads();                                   // B9 Wv ready

  // ---- P6: v = relu(h1 @ wv + bv); h1 dies
  zero8(accA);
  gemm_lds<NHID>(h1h, h1l, SHh, SHl, accA, g, l15);
  finalize(accA, bv, l15, true);
  __syncthreads();                                   // B10 Wv reads done (all waves)

  // ---- P7: stage vT (transposed, packed converts, b64 stores)
#pragma unroll
  for (int c = 0; c < 8; ++c){
    H4 hp, lp;
#pragma unroll
    for (int j = 0; j < 2; ++j){
      float v0 = accA[c][2*j], v1 = accA[c][2*j+1];
      fp16x2 h = __builtin_amdgcn_cvt_pkrtz(v0, v1);
      hp.p[j] = h;
      lp.p[j] = __builtin_amdgcn_cvt_pkrtz(v0 - (float)h[0], v1 - (float)h[1]);
    }
    const int idx = (16*c + l15)*WLD + w*16 + 4*g;
    *(half4v*)(SHh + idx) = hp.v;
    *(half4v*)(SHl + idx) = lp.v;
  }
  __syncthreads();                                   // B11 vT staged

  // ---- P8: h2 = att @ v (scaled); prefetch W1
  stage_load<2048>(wt + OFF_W1, 16384, wbh, wbl, tid);
  zero8(accB);
  gemm_lds<NHID>(afh, afl, SHh, SHl, accB, g, l15);
#pragma unroll
  for (int c = 0; c < 8; ++c)
#pragma unroll
    for (int i = 0; i < 4; ++i) accB[c][i] *= 6.103515625e-05f;  // 2^-14
  __syncthreads();                                   // B12 vT reads done
  stage_write<2048,16>(wbh, wbl, SHh, SHl, tid);
  __syncthreads();                                   // B13 W1 ready

  // ---- P9: MLP chain, fused conv+gemm, async staging
  stage_load<2048>(wt + OFF_W2, 16384, wbh, wbl, tid);
  zero8(accA);
  gemm_cv(accB, CVf, SHh, SHl, accA, g, l15);        // a1 = h2 @ W1
  finalize(accA, b1, l15, true);
  __syncthreads();                                   // B14 W1 reads done
  stage_write<2048,16>(wbh, wbl, SHh, SHl, tid);
  __syncthreads();                                   // B15 W2 ready

  stage_load<2048>(wt + OFF_W3, 16384, wbh, wbl, tid);
  zero8(accB);
  gemm_cv(accA, CVf, SHh, SHl, accB, g, l15);        // a2 = a1 @ W2
  finalize(accB, b2, l15, true);
  __syncthreads();                                   // B16 W2 reads done
  stage_write<2048,16>(wbh, wbl, SHh, SHl, tid);
  __syncthreads();                                   // B17 W3 ready

  stage_load<256>(wt + OFF_W4, 2048, wbh, wbl, tid);
  zero8(accA);
  gemm_cv(accB, CVf, SHh, SHl, accA, g, l15);        // a3 = a2 @ W3
  finalize(accA, b3, l15, true);
  __syncthreads();                                   // B18 W3 reads done
  stage_write<256,16>(wbh, wbl, SHh, SHl, tid);
  __syncthreads();                                   // B19 W4 ready

  // ---- P10: logits = a3 @ w4 + b4 (fused conv; 16-row padded weight in SH)
  f32x4 la = (f32x4){0.f,0.f,0.f,0.f};
#pragma unroll
  for (int kp = 0; kp < 4; ++kp){
    float fv[8];
    cv_row8(accA, kp, CVf, g, l15, fv);
    half8 ah, al;
    pack_split8(fv, ah, al);
    const int idx = l15*WLD + (4*kp + g)*8;
    half8 bh = *(const half8*)(SHh + idx);
    half8 bl = *(const half8*)(SHl + idx);
    MFMA3(ah, al, bh, bl, la);
  }
#pragma unroll
  for (int i = 0; i < 4; ++i)
    CVf[(4*g+i)*CVS2 + l15] = la[i] + ((l15 < NACT) ? b4[l15] : 0.0f);

  // ---- P11: log-softmax + threefry-gumbel + argmax (lanes g==0, one row each)
  if (g == 0){
    float lg[NACT]; float mxl = -3.0e38f;
#pragma unroll
    for (int c = 0; c < NACT; ++c){ lg[c] = CVf[l15*CVS2 + c]; mxl = fmaxf(mxl, lg[c]); }
    float s = 0.f; float p[NACT];
#pragma unroll
    for (int c = 0; c < NACT; ++c){ p[c] = expf(lg[c] - mxl); s += p[c]; }
    const int R = b*NN + w*16 + l15;
    const unsigned HHALF = (unsigned)(NB*NN*NACT/2);  // 589824
    float best = -3.0e38f; int bi = 0;
#pragma unroll
    for (int c = 0; c < NACT; ++c){
      float lp = logf(p[c] / s);
      unsigned e = (unsigned)(R*NACT + c);
      unsigned c0 = (e < HHALF) ? e : (e - HHALF);
      unsigned o0, o1; threefry(c0, c0 + HHALF, o0, o1);
      unsigned bits = (e < HHALF) ? o0 : o1;
      float u = __uint_as_float((bits >> 9) | 0x3f800000u) - 1.0f;
      float uu = fmaxf(1.17549435e-38f, u + 1.17549435e-38f);
      float gmb = -logf(-logf(uu));
      float scv = gmb + lp;
      if (scv > best){ best = scv; bi = c; }
    }
    out[R] = (float)bi;
  }
}

extern "C" void kernel_launch(void* const* d_in, const int* in_sizes, int n_in,
                              void* d_out, int out_size, void* d_ws, size_t ws_size,
                              hipStream_t stream){
  const float* x     = (const float*)d_in[0];
  const float* mask  = (const float*)d_in[1];
  const float* enc_w = (const float*)d_in[2];
  const float* enc_b = (const float*)d_in[3];
  const float* wv    = (const float*)d_in[4];
  const float* bv    = (const float*)d_in[5];
  const float* wk    = (const float*)d_in[6];
  const float* bk    = (const float*)d_in[7];
  const float* wq    = (const float*)d_in[8];
  const float* bq    = (const float*)d_in[9];
  const float* w1    = (const float*)d_in[10];
  const float* b1    = (const float*)d_in[11];
  const float* w2    = (const float*)d_in[12];
  const float* b2    = (const float*)d_in[13];
  const float* w3    = (const float*)d_in[14];
  const float* b3    = (const float*)d_in[15];
  const float* w4    = (const float*)d_in[16];
  const float* b4    = (const float*)d_in[17];
  _Float16* wt = (_Float16*)d_ws;
  float* out = (float*)d_out;

  prep_w<<<32, 256, 0, stream>>>(enc_w, wt+OFF_ENC, wt+OFF_ENC+8192, NOBS, NHID, NHID);
  prep_w<<<64, 256, 0, stream>>>(wv, wt+OFF_V, wt+OFF_V+16384, NHID, NHID, NHID);
  prep_w<<<64, 256, 0, stream>>>(wk, wt+OFF_K, wt+OFF_K+16384, NHID, NHID, NHID);
  prep_w<<<64, 256, 0, stream>>>(wq, wt+OFF_Q, wt+OFF_Q+16384, NHID, NHID, NHID);
  prep_w<<<64, 256, 0, stream>>>(w1, wt+OFF_W1, wt+OFF_W1+16384, NHID, NHID, NHID);
  prep_w<<<64, 256, 0, stream>>>(w2, wt+OFF_W2, wt+OFF_W2+16384, NHID, NHID, NHID);
  prep_w<<<64, 256, 0, stream>>>(w3, wt+OFF_W3, wt+OFF_W3+16384, NHID, NHID, NHID);
  prep_w<<<8,  256, 0, stream>>>(w4, wt+OFF_W4, wt+OFF_W4+2048, NHID, NACT, 16);

  dgn_main<<<NB, NTHR, 0, stream>>>(x, mask, wt, enc_b, bv, bk, bq,
                                    b1, b2, b3, b4, out);
}

// Round 8
// 175.071 us; speedup vs baseline: 2.8306x; 1.0682x over previous
//
#include <hip/hip_runtime.h>

#define NB   1024
#define NN   128
#define NOBS 64
#define NHID 128
#define NACT 9
#define NTHR 512
#define WLD  136   // padded LDS row stride in halves: conflict-free b128 column reads
#define CVS2 20    // CV row stride in dwords

// workspace offsets (fp16 elements): [hi | lo] per weight, transposed to [dout_pad][din]
#define OFF_ENC 0
#define OFF_V   16384
#define OFF_K   49152
#define OFF_Q   81920
#define OFF_W1  114688
#define OFF_W2  147456
#define OFF_W3  180224
#define OFF_W4  212992

typedef __attribute__((ext_vector_type(8))) _Float16 half8;
typedef __attribute__((ext_vector_type(4))) _Float16 half4v;
typedef __attribute__((ext_vector_type(2))) __fp16 fp16x2;
typedef __attribute__((ext_vector_type(4))) float f32x4;

union H8 { half8 v; fp16x2 p[4]; };
union H4 { half4v v; fp16x2 p[2]; };

// ---------- weight prep: fp16 hi/lo split (RNE), transposed [dout_pad][din] ----------
__global__ void prep_w(const float* __restrict__ w, _Float16* __restrict__ hi,
                       _Float16* __restrict__ lo, int din, int dout, int dpad){
  int i = blockIdx.x * blockDim.x + threadIdx.x;
  if (i >= dpad * din) return;
  int c = i / din, k = i - c * din;
  float v = (c < dout) ? w[(size_t)k * dout + c] : 0.0f;
  _Float16 h = (_Float16)v;
  hi[i] = h;
  lo[i] = (_Float16)(v - (float)h);
}

// ---------- activation split: 8 f32 -> fp16 hi/lo fragments via packed RTZ converts ----------
__device__ __forceinline__ void pack_split8(const float* fv, half8& ah, half8& al){
  H8 A, L;
#pragma unroll
  for (int j = 0; j < 4; ++j){
    fp16x2 h = __builtin_amdgcn_cvt_pkrtz(fv[2*j], fv[2*j+1]);
    float r0 = fv[2*j]   - (float)h[0];
    float r1 = fv[2*j+1] - (float)h[1];
    A.p[j] = h;
    L.p[j] = __builtin_amdgcn_cvt_pkrtz(r0, r1);
  }
  ah = A.v; al = L.v;
}

// ---------- threefry2x32, key = (0, 42) ----------
__device__ __forceinline__ void tf4(unsigned& v0, unsigned& v1, int r0,int r1,int r2,int r3){
  v0 += v1; v1 = (v1<<r0)|(v1>>(32-r0)); v1 ^= v0;
  v0 += v1; v1 = (v1<<r1)|(v1>>(32-r1)); v1 ^= v0;
  v0 += v1; v1 = (v1<<r2)|(v1>>(32-r2)); v1 ^= v0;
  v0 += v1; v1 = (v1<<r3)|(v1>>(32-r3)); v1 ^= v0;
}
__device__ __forceinline__ void threefry(unsigned x0, unsigned x1, unsigned& o0, unsigned& o1){
  const unsigned ks0 = 0u, ks1 = 42u, ks2 = 0x1BD11BDAu ^ 0u ^ 42u;
  unsigned v0 = x0 + ks0, v1 = x1 + ks1;
  tf4(v0,v1,13,15,26,6);  v0 += ks1; v1 += ks2 + 1u;
  tf4(v0,v1,17,29,16,24); v0 += ks2; v1 += ks0 + 2u;
  tf4(v0,v1,13,15,26,6);  v0 += ks0; v1 += ks1 + 3u;
  tf4(v0,v1,17,29,16,24); v0 += ks1; v1 += ks2 + 4u;
  tf4(v0,v1,13,15,26,6);  v0 += ks2; v1 += ks0 + 5u;
  o0 = v0; o1 = v1;
}

#define MFMA(a,b,c) __builtin_amdgcn_mfma_f32_16x16x32_f16((a),(b),(c),0,0,0)
// 3-term split product: ah*bh + al*bh + ah*bl  (al*bl ~ 2^-22, omitted)
#define MFMA3(ah,al,bh,bl,c) do{ (c)=MFMA((ah),(bh),(c)); (c)=MFMA((al),(bh),(c)); \
                                 (c)=MFMA((ah),(bl),(c)); }while(0)

__device__ __forceinline__ void zero8(f32x4* a){
#pragma unroll
  for (int c = 0; c < 8; ++c) a[c] = (f32x4){0.f,0.f,0.f,0.f};
}

// ---------- direct stage: global (linear) -> LDS (padded rows) ----------
template<int ROWS, int K>
__device__ __forceinline__ void stage_w(const _Float16* __restrict__ src,
                                        _Float16* dsth, _Float16* dstl, int tid){
  constexpr int GPR = K/8;
  constexpr int NG  = ROWS*GPR;
#pragma unroll
  for (int t0 = 0; t0 < NG; t0 += NTHR){
    int t = t0 + tid;
    if (NG % NTHR != 0 && t >= NG) break;
    int row = t / GPR, gc = t - row*GPR;
    int d = row*WLD + gc*8;
    *(half8*)(dsth + d) = *(const half8*)(src + t*8);
    *(half8*)(dstl + d) = *(const half8*)(src + ROWS*K + t*8);
  }
}

// ---------- async stage: issue global->reg early, write reg->LDS after barrier ----------
template<int NG>
__device__ __forceinline__ void stage_load(const _Float16* __restrict__ src, int loOff,
                                           half8* bh, half8* bl, int tid){
#pragma unroll
  for (int j = 0; j*NTHR < NG; ++j){
    int t = j*NTHR + tid;
    if (NG % NTHR != 0 && t >= NG) break;
    bh[j] = *(const half8*)(src + t*8);
    bl[j] = *(const half8*)(src + loOff + t*8);
  }
}
template<int NG, int GPR>
__device__ __forceinline__ void stage_write(const half8* bh, const half8* bl,
                                            _Float16* dsth, _Float16* dstl, int tid){
#pragma unroll
  for (int j = 0; j*NTHR < NG; ++j){
    int t = j*NTHR + tid;
    if (NG % NTHR != 0 && t >= NG) break;
    int row = t / GPR, gc = t - row*GPR;
    int d = row*WLD + gc*8;
    *(half8*)(dsth + d) = bh[j];
    *(half8*)(dstl + d) = bl[j];
  }
}

// dense GEMM: A-frags in regs, B in LDS padded [rows][WLD] hi/lo; setprio'd MFMA cluster
template<int K>
__device__ __forceinline__ void gemm_lds(const half8* fh, const half8* fl,
                                         const _Float16* SWh, const _Float16* SWl,
                                         f32x4* acc, int g, int l15){
  __builtin_amdgcn_s_setprio(1);
#pragma unroll
  for (int kp = 0; kp < K/32; ++kp){
#pragma unroll
    for (int c = 0; c < 8; ++c){
      const int idx = (16*c + l15)*WLD + (4*kp + g)*8;
      half8 bh = *(const half8*)(SWh + idx);
      half8 bl = *(const half8*)(SWl + idx);
      MFMA3(fh[kp], fl[kp], bh, bl, acc[c]);
    }
  }
  __builtin_amdgcn_s_setprio(0);
}

// acc chunk kp -> this lane's row-major 8 f32 (row l15, cols 8g..8g+7) via wave-private CV
__device__ __forceinline__ void cv_row8(const f32x4* pa, int kp, float* CVf,
                                        int g, int l15, float* fv){
  const int roff = l15*CVS2 + 8*(g & 1);
#pragma unroll
  for (int i = 0; i < 4; ++i) CVf[(4*g+i)*CVS2 + l15] = pa[2*kp][i];
  f32x4 a0 = *(const f32x4*)(CVf + roff);
  f32x4 a1 = *(const f32x4*)(CVf + roff + 4);
#pragma unroll
  for (int i = 0; i < 4; ++i) CVf[(4*g+i)*CVS2 + l15] = pa[2*kp+1][i];
  f32x4 b0 = *(const f32x4*)(CVf + roff);
  f32x4 b1 = *(const f32x4*)(CVf + roff + 4);
  f32x4 f0 = (g < 2) ? a0 : b0;
  f32x4 f1 = (g < 2) ? a1 : b1;
  fv[0]=f0[0]; fv[1]=f0[1]; fv[2]=f0[2]; fv[3]=f0[3];
  fv[4]=f1[0]; fv[5]=f1[1]; fv[6]=f1[2]; fv[7]=f1[3];
}

// full acc -> 4 fragment pairs
__device__ __forceinline__ void conv_all16(const f32x4* pa, float* CVf, int g, int l15,
                                           half8* fh, half8* fl){
#pragma unroll
  for (int kp = 0; kp < 4; ++kp){
    float fv[8];
    cv_row8(pa, kp, CVf, g, l15, fv);
    pack_split8(fv, fh[kp], fl[kp]);
  }
}

// fused conv + GEMM: per kp, convert A chunk then immediately run its 24 MFMAs
__device__ __forceinline__ void gemm_cv(const f32x4* pa, float* CVf,
                                        const _Float16* SWh, const _Float16* SWl,
                                        f32x4* acc, int g, int l15){
#pragma unroll
  for (int kp = 0; kp < 4; ++kp){
    float fv[8];
    cv_row8(pa, kp, CVf, g, l15, fv);
    half8 ah, al;
    pack_split8(fv, ah, al);
    __builtin_amdgcn_s_setprio(1);
#pragma unroll
    for (int c = 0; c < 8; ++c){
      const int idx = (16*c + l15)*WLD + (4*kp + g)*8;
      half8 bh = *(const half8*)(SWh + idx);
      half8 bl = *(const half8*)(SWl + idx);
      MFMA3(ah, al, bh, bl, acc[c]);
    }
    __builtin_amdgcn_s_setprio(0);
  }
}

__device__ __forceinline__ void finalize(f32x4* acc, const float* __restrict__ bias,
                                         int l15, bool relu){
#pragma unroll
  for (int c = 0; c < 8; ++c){
    float bb = bias[16*c + l15];
#pragma unroll
    for (int i = 0; i < 4; ++i){
      float v = acc[c][i] + bb;
      acc[c][i] = relu ? fmaxf(v, 0.0f) : v;
    }
  }
}

__global__ void __launch_bounds__(NTHR)
dgn_main(const float* __restrict__ x, const float* __restrict__ mask,
         const _Float16* __restrict__ wt,
         const float* __restrict__ encb, const float* __restrict__ bv,
         const float* __restrict__ bk, const float* __restrict__ bq,
         const float* __restrict__ b1, const float* __restrict__ b2,
         const float* __restrict__ b3, const float* __restrict__ b4,
         float* __restrict__ out){
  // static LDS: 2*34816 + 10240 = 79872 B -> 2 blocks/CU
  __shared__ __align__(16) _Float16 SHh[128*WLD];
  __shared__ __align__(16) _Float16 SHl[128*WLD];
  __shared__ __align__(16) float CVA[8*16*CVS2];

  const int tid  = threadIdx.x;
  const int lane = tid & 63;
  const int w    = tid >> 6;
  const int l15  = lane & 15;
  const int g    = lane >> 4;
  const int b    = blockIdx.x;
  float* CVf = CVA + w*16*CVS2;

  f32x4 accA[8], accB[8];
  half8 wbh[4], wbl[4];   // async weight staging buffer (32 VGPR)

  // ---- P0: direct stage enc weights
  stage_w<128, 64>(wt + OFF_ENC, SHh, SHl, tid);
  __syncthreads();                                   // B1 enc ready

  // ---- P1: h1 = relu(x @ enc_w + enc_b); prefetch Wq
  stage_load<2048>(wt + OFF_Q, 16384, wbh, wbl, tid);
  zero8(accA);
  {
    half8 xh[2], xl[2];
    const float* xrow = x + ((size_t)b*NN + w*16 + l15)*NOBS;
#pragma unroll
    for (int kp = 0; kp < 2; ++kp){
      float4 f0 = *(const float4*)(xrow + 32*kp + 8*g);
      float4 f1 = *(const float4*)(xrow + 32*kp + 8*g + 4);
      float fv[8] = {f0.x,f0.y,f0.z,f0.w,f1.x,f1.y,f1.z,f1.w};
      pack_split8(fv, xh[kp], xl[kp]);
    }
    gemm_lds<NOBS>(xh, xl, SHh, SHl, accA, g, l15);
  }
  finalize(accA, encb, l15, true);
  half8 h1h[4], h1l[4];
  conv_all16(accA, CVf, g, l15, h1h, h1l);           // wave-private CV: safe pre-barrier
  __syncthreads();                                   // B2 enc reads done
  stage_write<2048,16>(wbh, wbl, SHh, SHl, tid);
  __syncthreads();                                   // B3 Wq ready

  // ---- P2: q = relu(h1 @ wq + bq); prefetch Wk
  stage_load<2048>(wt + OFF_K, 16384, wbh, wbl, tid);
  zero8(accA);
  gemm_lds<NHID>(h1h, h1l, SHh, SHl, accA, g, l15);
  finalize(accA, bq, l15, true);
  half8 qfh[4], qfl[4];
  conv_all16(accA, CVf, g, l15, qfh, qfl);
  __syncthreads();                                   // B4 Wq reads done
  stage_write<2048,16>(wbh, wbl, SHh, SHl, tid);
  __syncthreads();                                   // B5 Wk ready

  // ---- P3: prefetch mask (acc layout); k = relu(h1 @ wk + bk) -> split into SH
  float mpre[32];
  {
    const float* mbase = mask + (size_t)b*NN*NN;
#pragma unroll
    for (int c = 0; c < 8; ++c)
#pragma unroll
      for (int i = 0; i < 4; ++i)
        mpre[c*4+i] = mbase[(w*16 + 4*g + i)*NN + 16*c + l15];
  }
  zero8(accA);
  gemm_lds<NHID>(h1h, h1l, SHh, SHl, accA, g, l15);
  finalize(accA, bk, l15, true);
  __syncthreads();                                   // B6 Wk reads done (all waves)
#pragma unroll
  for (int c = 0; c < 8; ++c)
#pragma unroll
    for (int i = 0; i < 4; ++i){
      float v = accA[c][i];
      _Float16 kh = (_Float16)v;
      const int idx = (w*16 + 4*g + i)*WLD + 16*c + l15;
      SHh[idx] = kh;
      SHl[idx] = (_Float16)(v - (float)kh);
    }
  __syncthreads();                                   // B7 k staged

  // ---- P4: scores = q @ k^T
  zero8(accB);
  gemm_lds<NHID>(qfh, qfl, SHh, SHl, accB, g, l15);
  __syncthreads();                                   // B8 k reads done

  // ---- P5: mask/clip -> h out, row-softmax, att frags; Wv prefetched under softmax
  half8 afh[4], afl[4];
  {
    float* hbase = out + (size_t)NB*NN + (size_t)b*NN*NN;
    float mx[4] = {-3.0e38f,-3.0e38f,-3.0e38f,-3.0e38f};
#pragma unroll
    for (int c = 0; c < 8; ++c)
#pragma unroll
      for (int i = 0; i < 4; ++i){
        const int row = w*16 + 4*g + i, col = 16*c + l15;
        float m = mpre[c*4+i];
        float hvv = fminf(fmaxf(accB[c][i]*m, 0.0f), 9.0e13f) - 9.0e15f*(1.0f - m);
        hbase[row*NN + col] = hvv;
        accB[c][i] = hvv;
        mx[i] = fmaxf(mx[i], hvv);
      }
    stage_load<2048>(wt + OFF_V, 16384, wbh, wbl, tid);
#pragma unroll
    for (int off = 8; off >= 1; off >>= 1)
#pragma unroll
      for (int i = 0; i < 4; ++i) mx[i] = fmaxf(mx[i], __shfl_xor(mx[i], off, 64));
    float sm[4] = {0.f,0.f,0.f,0.f};
#pragma unroll
    for (int c = 0; c < 8; ++c)
#pragma unroll
      for (int i = 0; i < 4; ++i){
        float e = __expf(accB[c][i] - mx[i]);
        accB[c][i] = e; sm[i] += e;
      }
#pragma unroll
    for (int off = 8; off >= 1; off >>= 1)
#pragma unroll
      for (int i = 0; i < 4; ++i) sm[i] += __shfl_xor(sm[i], off, 64);
    float inv[4];
#pragma unroll
    for (int i = 0; i < 4; ++i) inv[i] = 16384.0f / sm[i];  // 2^14 denorm guard
#pragma unroll
    for (int c = 0; c < 8; ++c)
#pragma unroll
      for (int i = 0; i < 4; ++i) accB[c][i] *= inv[i];
    conv_all16(accB, CVf, g, l15, afh, afl);
  }
  stage_write<2048,16>(wbh, wbl, SHh, SHl, tid);
  __syncthreads();                                   // B9 Wv ready

  // ---- P6: v = relu(h1 @ wv + bv); h1 dies
  zero8(accA);
  gemm_lds<NHID>(h1h, h1l, SHh, SHl, accA, g, l15);
  finalize(accA, bv, l15, true);
  __syncthreads();                                   // B10 Wv reads done (all waves)

  // ---- P7: stage vT (transposed, packed converts, b64 stores)
#pragma unroll
  for (int c = 0; c < 8; ++c){
    H4 hp, lp;
#pragma unroll
    for (int j = 0; j < 2; ++j){
      float v0 = accA[c][2*j], v1 = accA[c][2*j+1];
      fp16x2 h = __builtin_amdgcn_cvt_pkrtz(v0, v1);
      hp.p[j] = h;
      lp.p[j] = __builtin_amdgcn_cvt_pkrtz(v0 - (float)h[0], v1 - (float)h[1]);
    }
    const int idx = (16*c + l15)*WLD + w*16 + 4*g;
    *(half4v*)(SHh + idx) = hp.v;
    *(half4v*)(SHl + idx) = lp.v;
  }
  __syncthreads();                                   // B11 vT staged

  // ---- P8: h2 = att @ v (scaled); prefetch W1
  stage_load<2048>(wt + OFF_W1, 16384, wbh, wbl, tid);
  zero8(accB);
  gemm_lds<NHID>(afh, afl, SHh, SHl, accB, g, l15);
#pragma unroll
  for (int c = 0; c < 8; ++c)
#pragma unroll
    for (int i = 0; i < 4; ++i) accB[c][i] *= 6.103515625e-05f;  // 2^-14
  __syncthreads();                                   // B12 vT reads done
  stage_write<2048,16>(wbh, wbl, SHh, SHl, tid);
  __syncthreads();                                   // B13 W1 ready

  // ---- P9: MLP chain, fused conv+gemm, async staging
  stage_load<2048>(wt + OFF_W2, 16384, wbh, wbl, tid);
  zero8(accA);
  gemm_cv(accB, CVf, SHh, SHl, accA, g, l15);        // a1 = h2 @ W1
  finalize(accA, b1, l15, true);
  __syncthreads();                                   // B14 W1 reads done
  stage_write<2048,16>(wbh, wbl, SHh, SHl, tid);
  __syncthreads();                                   // B15 W2 ready

  stage_load<2048>(wt + OFF_W3, 16384, wbh, wbl, tid);
  zero8(accB);
  gemm_cv(accA, CVf, SHh, SHl, accB, g, l15);        // a2 = a1 @ W2
  finalize(accB, b2, l15, true);
  __syncthreads();                                   // B16 W2 reads done
  stage_write<2048,16>(wbh, wbl, SHh, SHl, tid);
  __syncthreads();                                   // B17 W3 ready

  zero8(accA);
  gemm_cv(accB, CVf, SHh, SHl, accA, g, l15);        // a3 = a2 @ W3
  finalize(accA, b3, l15, true);
  // no barrier needed: W4 is read from global (L2), SH is not touched again

  // ---- P10: logits = a3 @ w4 + b4 (W4 direct from L2; fused conv)
  f32x4 la = (f32x4){0.f,0.f,0.f,0.f};
#pragma unroll
  for (int kp = 0; kp < 4; ++kp){
    float fv[8];
    cv_row8(accA, kp, CVf, g, l15, fv);
    half8 ah, al;
    pack_split8(fv, ah, al);
    const int wof = l15*NHID + (4*kp + g)*8;
    half8 bh = *(const half8*)(wt + OFF_W4 + wof);
    half8 bl = *(const half8*)(wt + OFF_W4 + 2048 + wof);
    MFMA3(ah, al, bh, bl, la);
  }
#pragma unroll
  for (int i = 0; i < 4; ++i)
    CVf[(4*g+i)*CVS2 + l15] = la[i] + ((l15 < NACT) ? b4[l15] : 0.0f);

  // ---- P11: log-softmax + threefry-gumbel + argmax (lanes g==0, one row each)
  if (g == 0){
    float lg[NACT]; float mxl = -3.0e38f;
#pragma unroll
    for (int c = 0; c < NACT; ++c){ lg[c] = CVf[l15*CVS2 + c]; mxl = fmaxf(mxl, lg[c]); }
    float s = 0.f; float p[NACT];
#pragma unroll
    for (int c = 0; c < NACT; ++c){ p[c] = expf(lg[c] - mxl); s += p[c]; }
    const int R = b*NN + w*16 + l15;
    const unsigned HHALF = (unsigned)(NB*NN*NACT/2);  // 589824
    float best = -3.0e38f; int bi = 0;
#pragma unroll
    for (int c = 0; c < NACT; ++c){
      float lp = logf(p[c] / s);
      unsigned e = (unsigned)(R*NACT + c);
      unsigned c0 = (e < HHALF) ? e : (e - HHALF);
      unsigned o0, o1; threefry(c0, c0 + HHALF, o0, o1);
      unsigned bits = (e < HHALF) ? o0 : o1;
      float u = __uint_as_float((bits >> 9) | 0x3f800000u) - 1.0f;
      float uu = fmaxf(1.17549435e-38f, u + 1.17549435e-38f);
      float gmb = -logf(-logf(uu));
      float scv = gmb + lp;
      if (scv > best){ best = scv; bi = c; }
    }
    out[R] = (float)bi;
  }
}

extern "C" void kernel_launch(void* const* d_in, const int* in_sizes, int n_in,
                              void* d_out, int out_size, void* d_ws, size_t ws_size,
                              hipStream_t stream){
  const float* x     = (const float*)d_in[0];
  const float* mask  = (const float*)d_in[1];
  const float* enc_w = (const float*)d_in[2];
  const float* enc_b = (const float*)d_in[3];
  const float* wv    = (const float*)d_in[4];
  const float* bv    = (const float*)d_in[5];
  const float* wk    = (const float*)d_in[6];
  const float* bk    = (const float*)d_in[7];
  const float* wq    = (const float*)d_in[8];
  const float* bq    = (const float*)d_in[9];
  const float* w1    = (const float*)d_in[10];
  const float* b1    = (const float*)d_in[11];
  const float* w2    = (const float*)d_in[12];
  const float* b2    = (const float*)d_in[13];
  const float* w3    = (const float*)d_in[14];
  const float* b3    = (const float*)d_in[15];
  const float* w4    = (const float*)d_in[16];
  const float* b4    = (const float*)d_in[17];
  _Float16* wt = (_Float16*)d_ws;
  float* out = (float*)d_out;

  prep_w<<<32, 256, 0, stream>>>(enc_w, wt+OFF_ENC, wt+OFF_ENC+8192, NOBS, NHID, NHID);
  prep_w<<<64, 256, 0, stream>>>(wv, wt+OFF_V, wt+OFF_V+16384, NHID, NHID, NHID);
  prep_w<<<64, 256, 0, stream>>>(wk, wt+OFF_K, wt+OFF_K+16384, NHID, NHID, NHID);
  prep_w<<<64, 256, 0, stream>>>(wq, wt+OFF_Q, wt+OFF_Q+16384, NHID, NHID, NHID);
  prep_w<<<64, 256, 0, stream>>>(w1, wt+OFF_W1, wt+OFF_W1+16384, NHID, NHID, NHID);
  prep_w<<<64, 256, 0, stream>>>(w2, wt+OFF_W2, wt+OFF_W2+16384, NHID, NHID, NHID);
  prep_w<<<64, 256, 0, stream>>>(w3, wt+OFF_W3, wt+OFF_W3+16384, NHID, NHID, NHID);
  prep_w<<<8,  256, 0, stream>>>(w4, wt+OFF_W4, wt+OFF_W4+2048, NHID, NACT, 16);

  dgn_main<<<NB, NTHR, 0, stream>>>(x, mask, wt, enc_b, bv, bk, bq,
                                    b1, b2, b3, b4, out);
}